// Round 1
// baseline (1302.410 us; speedup 1.0000x reference)
//
#include <hip/hip_runtime.h>
#include <math.h>

#define BB   64
#define NN   784
#define DD   768
#define HH   32
#define HD24 24
#define MM   785
#define HIDN 3072
#define QSCALE 0.20412414523193154f
#define LNEPS 1e-6f

// ---- workspace layout (float offsets) ----
#define WS_S1    49152
#define WS_C0    51200
#define WS_RS    53248      // [64][785] rsigma
#define WS_RM    103488     // [64][785] rsigma*mu
#define WS_A2    153728
#define WS_WM    155776
#define WS_C1    157824     // [64][768]
#define WS_Y     206976     // [64][768]
#define WS_H2    256128     // [64][3072]
#define WS_ZP    452736     // [4][64][768]
#define WS_E     649344     // gqkT [64][768][32] then E/W [64][32][800]
#define WS_T     2287744    // t [64][785][32] then r [64][32][768]

// ============================================================
// K0: per-b q-side prep: LN(cls), q=(nc@Wq+bq)*SCALE, qk per head,
// fold (I+w1), write gqkT[b][d][h]=g_d*qkf, s1, c0.
// ============================================================
__global__ __launch_bounds__(256) void k_qprep(
    const float* __restrict__ x_cls,
    const float* __restrict__ g1, const float* __restrict__ b1,
    const float* __restrict__ Wq, const float* __restrict__ bq,
    const float* __restrict__ Wk, const float* __restrict__ bk,
    const float* __restrict__ w1W, const float* __restrict__ w1b,
    float* __restrict__ ws)
{
  const int b = blockIdx.x;
  const int t = threadIdx.x;
  const int lane = t & 63;
  const int wid = t >> 6;

  __shared__ __align__(16) float nc[DD];
  __shared__ __align__(16) float qv[DD];
  __shared__ float T1[HH * HH];
  __shared__ float redS[4], redQ[4];
  __shared__ float part[4][HH];
  __shared__ float part2[4][HH];
  __shared__ float bqs_sh[HH];
  __shared__ float mu_sh, rs_sh;

  // LN stats of cls row
  float xv[3];
  float s = 0.f, q2 = 0.f;
#pragma unroll
  for (int k = 0; k < 3; ++k) {
    float v = x_cls[(size_t)b * DD + t + 256 * k];
    xv[k] = v; s += v; q2 += v * v;
  }
#pragma unroll
  for (int off = 1; off < 64; off <<= 1) { s += __shfl_xor(s, off); q2 += __shfl_xor(q2, off); }
  if (lane == 0) { redS[wid] = s; redQ[wid] = q2; }
  // T1 = I + w1 (src-major: T1[g][h], out index h)
  for (int i = t; i < HH * HH; i += 256) {
    int g = i >> 5, h = i & 31;
    T1[i] = w1W[i] + ((g == h) ? 1.f : 0.f);
  }
  __syncthreads();
  if (t == 0) {
    float ss = redS[0] + redS[1] + redS[2] + redS[3];
    float qq = redQ[0] + redQ[1] + redQ[2] + redQ[3];
    float mu = ss * (1.f / DD);
    float var = qq * (1.f / DD) - mu * mu;
    mu_sh = mu; rs_sh = rsqrtf(var + LNEPS);
  }
  __syncthreads();
  {
    float mu = mu_sh, rs = rs_sh;
#pragma unroll
    for (int k = 0; k < 3; ++k) {
      int d = t + 256 * k;
      nc[d] = (xv[k] - mu) * rs * g1[d] + b1[d];
    }
  }
  __syncthreads();

  // q = (nc @ Wq + bq) * QSCALE
#pragma unroll 1
  for (int k = 0; k < 3; ++k) {
    int doo = t + 256 * k;
    float acc = bq[doo];
#pragma unroll 4
    for (int di = 0; di < DD; ++di)
      acc += nc[di] * Wq[(size_t)di * DD + doo];
    qv[doo] = acc * QSCALE;
  }
  __syncthreads();

  // qk per d; fold with T1; write gqkT; accumulate s1, bqs
  float s1_loc[HH], bqs_loc[HH];
#pragma unroll
  for (int h = 0; h < HH; ++h) { s1_loc[h] = 0.f; bqs_loc[h] = 0.f; }
  const float4* qv4 = (const float4*)qv;
#pragma unroll 1
  for (int k = 0; k < 3; ++k) {
    int d = t + 256 * k;
    const float4* wk4 = (const float4*)(Wk + (size_t)d * DD);
    float qk[HH];
#pragma unroll
    for (int g = 0; g < HH; ++g) {
      float a = 0.f;
#pragma unroll
      for (int c = 0; c < 6; ++c) {
        float4 w = wk4[g * 6 + c];
        float4 p = qv4[g * 6 + c];
        a += w.x * p.x + w.y * p.y + w.z * p.z + w.w * p.w;
      }
      qk[g] = a;
    }
    float bd = b1[d], gd = g1[d];
#pragma unroll
    for (int g = 0; g < HH; ++g) bqs_loc[g] += bd * qk[g];
    float* gout = ws + WS_E + ((size_t)b * DD + d) * HH;
#pragma unroll
    for (int h = 0; h < HH; ++h) {
      float f = 0.f;
#pragma unroll
      for (int g = 0; g < HH; ++g) f += qk[g] * T1[g * HH + h];
      float gq = gd * f;
      s1_loc[h] += gq;
      gout[h] = gq;
    }
  }

#pragma unroll
  for (int h = 0; h < HH; ++h) {
    float v = s1_loc[h];
#pragma unroll
    for (int off = 1; off < 64; off <<= 1) v += __shfl_xor(v, off);
    if (lane == 0) part[wid][h] = v;
    float u = bqs_loc[h];
#pragma unroll
    for (int off = 1; off < 64; off <<= 1) u += __shfl_xor(u, off);
    if (lane == 0) part2[wid][h] = u;
  }
  __syncthreads();
  if (t < HH) {
    int h = t;
    ws[WS_S1 + b * HH + h] = part[0][h] + part[1][h] + part[2][h] + part[3][h];
    float cb = 0.f;
#pragma unroll
    for (int j = 0; j < HD24; ++j) cb += bk[h * HD24 + j] * qv[h * HD24 + j];
    bqs_sh[h] = part2[0][h] + part2[1][h] + part2[2][h] + part2[3][h] + cb;
  }
  __syncthreads();
  if (t < HH) {
    int h = t;
    float c0 = w1b[h];
#pragma unroll
    for (int g = 0; g < HH; ++g) c0 += T1[g * HH + h] * bqs_sh[g];
    ws[WS_C0 + b * HH + h] = c0;
  }
}

// ============================================================
// K1: per (b, 256-row tile): stage u rows, copy x_img->out,
// LN stats per row, t[b][m][h] = sum_d u[m,d]*gqkT[d,h].
// ============================================================
__global__ __launch_bounds__(256) void k_main1(
    const float* __restrict__ x_cls, const float* __restrict__ x_img,
    float* __restrict__ out, float* __restrict__ ws)
{
  const int b = blockIdx.y;
  const int m0 = blockIdx.x * 256;
  const int t = threadIdx.x;
  const int tx = t & 3;       // head group: h0 = 8*tx
  const int ty = t >> 2;      // rows ty + 64*i
  const int prow = t >> 3;    // staging row / gq d-row
  const int pcol = (t & 7) * 4;

  __shared__ __align__(16) float u_lds[256][36];
  __shared__ __align__(16) float gq_lds[32][36];

  float* out_img = out + (size_t)BB * DD;
  const float* gq_src = ws + WS_E + (size_t)b * DD * HH;

  float acc[4][8];
#pragma unroll
  for (int i = 0; i < 4; ++i)
#pragma unroll
    for (int j = 0; j < 8; ++j) acc[i][j] = 0.f;
  float ssum = 0.f, ssq = 0.f;

  float4 pf[8];
  float4 pfg;

  auto k1_load = [&](int dc) {
#pragma unroll
    for (int kk = 0; kk < 8; ++kk) {
      int m = m0 + prow + 32 * kk;
      if (m < MM) {
        const float* src = (m == 0) ? (x_cls + (size_t)b * DD)
                                    : (x_img + ((size_t)b * NN + (m - 1)) * DD);
        pf[kk] = *(const float4*)(src + dc * 32 + pcol);
      } else {
        pf[kk] = make_float4(0.f, 0.f, 0.f, 0.f);
      }
    }
    pfg = *(const float4*)(gq_src + (size_t)(dc * 32 + prow) * HH + pcol);
  };
  auto k1_store = [&](int dc) {
#pragma unroll
    for (int kk = 0; kk < 8; ++kk) {
      int r = prow + 32 * kk;
      int m = m0 + r;
      *(float4*)&u_lds[r][pcol] = pf[kk];
      if (m >= 1 && m < MM)
        *(float4*)(out_img + ((size_t)b * NN + (m - 1)) * DD + dc * 32 + pcol) = pf[kk];
    }
    *(float4*)&gq_lds[prow][pcol] = pfg;
  };

  k1_load(0);
  k1_store(0);
  __syncthreads();

  for (int dc = 0; dc < 24; ++dc) {
    if (dc < 23) k1_load(dc + 1);   // prefetch overlaps compute
    // row stats: thread t owns row t
#pragma unroll 8
    for (int j = 0; j < 32; ++j) {
      float v = u_lds[t][(t + j) & 31];
      ssum += v; ssq += v * v;
    }
#pragma unroll 2
    for (int dd = 0; dd < 32; ++dd) {
      float4 g0 = *(const float4*)&gq_lds[dd][8 * tx];
      float4 g1 = *(const float4*)&gq_lds[dd][8 * tx + 4];
#pragma unroll
      for (int i = 0; i < 4; ++i) {
        float uv = u_lds[ty + 64 * i][dd];
        acc[i][0] += uv * g0.x; acc[i][1] += uv * g0.y;
        acc[i][2] += uv * g0.z; acc[i][3] += uv * g0.w;
        acc[i][4] += uv * g1.x; acc[i][5] += uv * g1.y;
        acc[i][6] += uv * g1.z; acc[i][7] += uv * g1.w;
      }
    }
    __syncthreads();
    if (dc < 23) k1_store(dc + 1);
    __syncthreads();
  }

  float* tmat = ws + WS_T;
#pragma unroll
  for (int i = 0; i < 4; ++i) {
    int m = m0 + ty + 64 * i;
    if (m < MM) {
      float* dst = tmat + ((size_t)b * MM + m) * HH + 8 * tx;
      *(float4*)dst = make_float4(acc[i][0], acc[i][1], acc[i][2], acc[i][3]);
      *(float4*)(dst + 4) = make_float4(acc[i][4], acc[i][5], acc[i][6], acc[i][7]);
    }
  }
  {
    int m = m0 + t;
    if (m < MM) {
      float mu = ssum * (1.f / DD);
      float var = ssq * (1.f / DD) - mu * mu;
      float rs = rsqrtf(var + LNEPS);
      ws[WS_RS + (size_t)b * MM + m] = rs;
      ws[WS_RM + (size_t)b * MM + m] = rs * mu;
    }
  }
}

// ============================================================
// K2: per-b softmax over m + post-softmax talking heads.
// attn1 = rs*t - rm*s1 + c0; e=exp(attn1-max); attn2 = e @ T2p + w2b;
// w = attn2*rs stored over E; A2, WM reduced.
// ============================================================
__global__ __launch_bounds__(256) void k_softmax(
    const float* __restrict__ w2W, const float* __restrict__ w2b,
    float* __restrict__ ws)
{
  const int b = blockIdx.x;
  const int t = threadIdx.x;
  const int lane = t & 63;
  const int wid = t >> 6;

  __shared__ float s1_sh[HH], c0_sh[HH], w2b_sh[HH];
  __shared__ float part[4][HH];
  __shared__ float mx_sh[HH], sum_sh[HH];
  __shared__ float T2p[HH * HH];

  if (t < HH) {
    s1_sh[t] = ws[WS_S1 + b * HH + t];
    c0_sh[t] = ws[WS_C0 + b * HH + t];
    w2b_sh[t] = w2b[t];
  }
  __syncthreads();

  const float* tmat = ws + WS_T + (size_t)b * MM * HH;
  const float* rs_p = ws + WS_RS + (size_t)b * MM;
  const float* rm_p = ws + WS_RM + (size_t)b * MM;
  float* E = ws + WS_E + (size_t)b * HH * 800;

  float lv[HH];
#pragma unroll
  for (int h = 0; h < HH; ++h) lv[h] = -3.0e38f;
#pragma unroll 1
  for (int k = 0; k < 4; ++k) {
    int m = t + 256 * k;
    if (m < MM) {
      float rs = rs_p[m], rm = rm_p[m];
      const float4* tr = (const float4*)(tmat + (size_t)m * HH);
#pragma unroll
      for (int qq = 0; qq < 8; ++qq) {
        float4 tv = tr[qq];
        int h = qq * 4;
        lv[h+0] = fmaxf(lv[h+0], rs*tv.x - rm*s1_sh[h+0] + c0_sh[h+0]);
        lv[h+1] = fmaxf(lv[h+1], rs*tv.y - rm*s1_sh[h+1] + c0_sh[h+1]);
        lv[h+2] = fmaxf(lv[h+2], rs*tv.z - rm*s1_sh[h+2] + c0_sh[h+2]);
        lv[h+3] = fmaxf(lv[h+3], rs*tv.w - rm*s1_sh[h+3] + c0_sh[h+3]);
      }
    }
  }
#pragma unroll
  for (int h = 0; h < HH; ++h) {
    float v = lv[h];
#pragma unroll
    for (int off = 1; off < 64; off <<= 1) v = fmaxf(v, __shfl_xor(v, off));
    if (lane == 0) part[wid][h] = v;
  }
  __syncthreads();
  if (t < HH) mx_sh[t] = fmaxf(fmaxf(part[0][t], part[1][t]), fmaxf(part[2][t], part[3][t]));
  __syncthreads();

#pragma unroll
  for (int h = 0; h < HH; ++h) lv[h] = 0.f;
#pragma unroll 1
  for (int k = 0; k < 4; ++k) {
    int m = t + 256 * k;
    if (m < MM) {
      float rs = rs_p[m], rm = rm_p[m];
      const float4* tr = (const float4*)(tmat + (size_t)m * HH);
#pragma unroll
      for (int qq = 0; qq < 8; ++qq) {
        float4 tv = tr[qq];
        int h = qq * 4;
        float e0 = __expf(rs*tv.x - rm*s1_sh[h+0] + c0_sh[h+0] - mx_sh[h+0]);
        float e1 = __expf(rs*tv.y - rm*s1_sh[h+1] + c0_sh[h+1] - mx_sh[h+1]);
        float e2 = __expf(rs*tv.z - rm*s1_sh[h+2] + c0_sh[h+2] - mx_sh[h+2]);
        float e3 = __expf(rs*tv.w - rm*s1_sh[h+3] + c0_sh[h+3] - mx_sh[h+3]);
        lv[h+0] += e0; lv[h+1] += e1; lv[h+2] += e2; lv[h+3] += e3;
        E[(size_t)(h+0)*800 + m] = e0;
        E[(size_t)(h+1)*800 + m] = e1;
        E[(size_t)(h+2)*800 + m] = e2;
        E[(size_t)(h+3)*800 + m] = e3;
      }
    }
  }
#pragma unroll
  for (int h = 0; h < HH; ++h) {
    float v = lv[h];
#pragma unroll
    for (int off = 1; off < 64; off <<= 1) v += __shfl_xor(v, off);
    if (lane == 0) part[wid][h] = v;
  }
  __syncthreads();
  if (t < HH) sum_sh[t] = part[0][t] + part[1][t] + part[2][t] + part[3][t];
  __syncthreads();

  // T2p[g][h] = (I + w2)[g][h] / sum[g]
  for (int i = t; i < HH * HH; i += 256) {
    int g = i >> 5, h = i & 31;
    T2p[i] = (w2W[i] + ((g == h) ? 1.f : 0.f)) / sum_sh[g];
  }
  __syncthreads();

  float A2l[HH], WMl[HH];
#pragma unroll
  for (int h = 0; h < HH; ++h) { A2l[h] = 0.f; WMl[h] = 0.f; }
#pragma unroll 1
  for (int k = 0; k < 4; ++k) {
    int m = t + 256 * k;
    if (m < 800) {
      if (m < MM) {
        float eg[HH];
#pragma unroll
        for (int g = 0; g < HH; ++g) eg[g] = E[(size_t)g * 800 + m];
        float rs = rs_p[m], rm = rm_p[m];
#pragma unroll
        for (int h = 0; h < HH; ++h) {
          float a2 = w2b_sh[h];
#pragma unroll
          for (int g = 0; g < HH; ++g) a2 += eg[g] * T2p[g * HH + h];
          A2l[h] += a2;
          WMl[h] += a2 * rm;
          E[(size_t)h * 800 + m] = a2 * rs;   // in-place: this thread owns column m
        }
      } else {
#pragma unroll
        for (int h = 0; h < HH; ++h) E[(size_t)h * 800 + m] = 0.f;  // zero pad
      }
    }
  }
#pragma unroll
  for (int h = 0; h < HH; ++h) {
    float v = A2l[h];
#pragma unroll
    for (int off = 1; off < 64; off <<= 1) v += __shfl_xor(v, off);
    if (lane == 0) part[wid][h] = v;
  }
  __syncthreads();
  if (t < HH) ws[WS_A2 + b * HH + t] = part[0][t] + part[1][t] + part[2][t] + part[3][t];
  __syncthreads();
#pragma unroll
  for (int h = 0; h < HH; ++h) {
    float v = WMl[h];
#pragma unroll
    for (int off = 1; off < 64; off <<= 1) v += __shfl_xor(v, off);
    if (lane == 0) part[wid][h] = v;
  }
  __syncthreads();
  if (t < HH) ws[WS_WM + b * HH + t] = part[0][t] + part[1][t] + part[2][t] + part[3][t];
}

// ============================================================
// K3: r[b][h][d] = sum_m w[b][h][m] * u[b][m][d]  (second x_img pass)
// ============================================================
__global__ __launch_bounds__(128) void k_wsum(
    const float* __restrict__ x_cls, const float* __restrict__ x_img,
    float* __restrict__ ws)
{
  const int b = blockIdx.y;
  const int d0 = blockIdx.x * 128;
  const int t = threadIdx.x;
  const int hg = t >> 4;   // heads 4*hg..
  const int dg = t & 15;   // cols 4*dg and 64+4*dg

  __shared__ __align__(16) float u_s[32][132];
  __shared__ __align__(16) float w_s[32][36];

  const float* W = ws + WS_E + (size_t)b * HH * 800;

  float acc[4][8];
#pragma unroll
  for (int i = 0; i < 4; ++i)
#pragma unroll
    for (int j = 0; j < 8; ++j) acc[i][j] = 0.f;

  float4 pu[8];
  float4 pw[2];

  auto k3_load = [&](int mc) {
#pragma unroll
    for (int p = 0; p < 8; ++p) {
      int r = (t >> 5) + p * 4;
      int c = (t & 31) * 4;
      int m = mc * 32 + r;
      if (m < MM) {
        const float* src = (m == 0) ? (x_cls + (size_t)b * DD)
                                    : (x_img + ((size_t)b * NN + (m - 1)) * DD);
        pu[p] = *(const float4*)(src + d0 + c);
      } else pu[p] = make_float4(0.f, 0.f, 0.f, 0.f);
    }
    int h = t >> 2;
#pragma unroll
    for (int pp = 0; pp < 2; ++pp) {
      int c = (t & 3) * 4 + pp * 16;
      pw[pp] = *(const float4*)(W + (size_t)h * 800 + mc * 32 + c);
    }
  };
  auto k3_store = [&]() {
#pragma unroll
    for (int p = 0; p < 8; ++p) {
      int r = (t >> 5) + p * 4;
      int c = (t & 31) * 4;
      *(float4*)&u_s[r][c] = pu[p];
    }
    int h = t >> 2;
#pragma unroll
    for (int pp = 0; pp < 2; ++pp) {
      int c = (t & 3) * 4 + pp * 16;
      *(float4*)&w_s[h][c] = pw[pp];
    }
  };

  k3_load(0);
  k3_store();
  __syncthreads();

  for (int mc = 0; mc < 25; ++mc) {
    if (mc < 24) k3_load(mc + 1);
#pragma unroll 2
    for (int mm = 0; mm < 32; ++mm) {
      float4 u0 = *(const float4*)&u_s[mm][4 * dg];
      float4 u1 = *(const float4*)&u_s[mm][64 + 4 * dg];
      float w0 = w_s[4 * hg + 0][mm];
      float w1 = w_s[4 * hg + 1][mm];
      float w2 = w_s[4 * hg + 2][mm];
      float w3 = w_s[4 * hg + 3][mm];
      acc[0][0] += w0*u0.x; acc[0][1] += w0*u0.y; acc[0][2] += w0*u0.z; acc[0][3] += w0*u0.w;
      acc[0][4] += w0*u1.x; acc[0][5] += w0*u1.y; acc[0][6] += w0*u1.z; acc[0][7] += w0*u1.w;
      acc[1][0] += w1*u0.x; acc[1][1] += w1*u0.y; acc[1][2] += w1*u0.z; acc[1][3] += w1*u0.w;
      acc[1][4] += w1*u1.x; acc[1][5] += w1*u1.y; acc[1][6] += w1*u1.z; acc[1][7] += w1*u1.w;
      acc[2][0] += w2*u0.x; acc[2][1] += w2*u0.y; acc[2][2] += w2*u0.z; acc[2][3] += w2*u0.w;
      acc[2][4] += w2*u1.x; acc[2][5] += w2*u1.y; acc[2][6] += w2*u1.z; acc[2][7] += w2*u1.w;
      acc[3][0] += w3*u0.x; acc[3][1] += w3*u0.y; acc[3][2] += w3*u0.z; acc[3][3] += w3*u0.w;
      acc[3][4] += w3*u1.x; acc[3][5] += w3*u1.y; acc[3][6] += w3*u1.z; acc[3][7] += w3*u1.w;
    }
    __syncthreads();
    if (mc < 24) k3_store();
    __syncthreads();
  }

  float* R = ws + WS_T;
#pragma unroll
  for (int i = 0; i < 4; ++i) {
    int h = 4 * hg + i;
    float* dst = R + ((size_t)b * HH + h) * DD + d0;
    *(float4*)(dst + 4 * dg)      = make_float4(acc[i][0], acc[i][1], acc[i][2], acc[i][3]);
    *(float4*)(dst + 64 + 4 * dg) = make_float4(acc[i][4], acc[i][5], acc[i][6], acc[i][7]);
  }
}

// ============================================================
// K4a: per-b: o = agg@Wv + A2*bv; c1 = x_cls + o@projW + projb; LN2 -> y
// ============================================================
__global__ __launch_bounds__(256) void k_proj(
    const float* __restrict__ x_cls,
    const float* __restrict__ g1, const float* __restrict__ b1,
    const float* __restrict__ Wv, const float* __restrict__ bv,
    const float* __restrict__ projW, const float* __restrict__ projb,
    const float* __restrict__ g2, const float* __restrict__ b2,
    float* __restrict__ ws)
{
  const int b = blockIdx.x;
  const int t = threadIdx.x;
  const int lane = t & 63, wid = t >> 6;

  __shared__ float agg_s[HH][193];
  __shared__ __align__(16) float o_s[DD];
  __shared__ float A2_s[HH], WM_s[HH];
  __shared__ float redS[4], redQ[4];
  __shared__ float mu_sh, rs_sh;

  if (t < HH) { A2_s[t] = ws[WS_A2 + b * HH + t]; WM_s[t] = ws[WS_WM + b * HH + t]; }
  __syncthreads();

  float oacc[3];
#pragma unroll
  for (int k = 0; k < 3; ++k) {
    int oc = t + 256 * k;
    oacc[k] = A2_s[oc / HD24] * bv[oc];
  }

  const float* R = ws + WS_T + (size_t)b * HH * DD;

#pragma unroll 1
  for (int cc = 0; cc < 4; ++cc) {
    for (int i = t; i < HH * 192; i += 256) {
      int h = i / 192, dd = i - h * 192;
      int d = cc * 192 + dd;
      agg_s[h][dd] = g1[d] * (R[(size_t)h * DD + d] - WM_s[h]) + b1[d] * A2_s[h];
    }
    __syncthreads();
#pragma unroll 1
    for (int k = 0; k < 3; ++k) {
      int oc = t + 256 * k;
      int h = oc / HD24;
      float a = oacc[k];
      const float* wvp = Wv + (size_t)cc * 192 * DD + oc;
#pragma unroll 4
      for (int dd = 0; dd < 192; ++dd)
        a += agg_s[h][dd] * wvp[(size_t)dd * DD];
      oacc[k] = a;
    }
    __syncthreads();
  }
#pragma unroll
  for (int k = 0; k < 3; ++k) o_s[t + 256 * k] = oacc[k];
  __syncthreads();

  float c1v[3];
  float s = 0.f, q2 = 0.f;
#pragma unroll 1
  for (int k = 0; k < 3; ++k) {
    int oc = t + 256 * k;
    float a = projb[oc];
    const float* pw = projW + oc;
#pragma unroll 4
    for (int d = 0; d < DD; ++d)
      a += o_s[d] * pw[(size_t)d * DD];
    a += x_cls[(size_t)b * DD + oc];
    c1v[k] = a;
    ws[WS_C1 + (size_t)b * DD + oc] = a;
    s += a; q2 += a * a;
  }
#pragma unroll
  for (int off = 1; off < 64; off <<= 1) { s += __shfl_xor(s, off); q2 += __shfl_xor(q2, off); }
  if (lane == 0) { redS[wid] = s; redQ[wid] = q2; }
  __syncthreads();
  if (t == 0) {
    float ss = redS[0] + redS[1] + redS[2] + redS[3];
    float qq = redQ[0] + redQ[1] + redQ[2] + redQ[3];
    float mu = ss * (1.f / DD);
    mu_sh = mu;
    rs_sh = rsqrtf(qq * (1.f / DD) - mu * mu + LNEPS);
  }
  __syncthreads();
  {
    float mu = mu_sh, rs = rs_sh;
#pragma unroll
    for (int k = 0; k < 3; ++k) {
      int oc = t + 256 * k;
      ws[WS_Y + (size_t)b * DD + oc] = (c1v[k] - mu) * rs * g2[oc] + b2[oc];
    }
  }
}

// ============================================================
// K4b: fc1 (grouped) + exact GELU + channel shuffle -> H2
// ============================================================
__global__ __launch_bounds__(256) void k_fc1(
    const float* __restrict__ fc1W, const float* __restrict__ fc1b,
    float* __restrict__ ws)
{
  const int g = blockIdx.x / 24;
  const int oc0 = (blockIdx.x % 24) * 64;
  const int t = threadIdx.x;
  const int txo = t & 15, tyb = t >> 4;

  __shared__ float y_s[64][65];
  __shared__ float w_s[64][65];

  float acc[4][4];
#pragma unroll
  for (int i = 0; i < 4; ++i)
#pragma unroll
    for (int j = 0; j < 4; ++j) acc[i][j] = 0.f;

  const float* Y = ws + WS_Y;

#pragma unroll 1
  for (int kc = 0; kc < 6; ++kc) {
    int r = t >> 2;
    int cb = (t & 3) * 4;
#pragma unroll
    for (int p = 0; p < 4; ++p) {
      int c = cb + p * 16;
      float4 v = *(const float4*)(Y + (size_t)r * DD + g * 384 + kc * 64 + c);
      y_s[r][c] = v.x; y_s[r][c+1] = v.y; y_s[r][c+2] = v.z; y_s[r][c+3] = v.w;
      float4 w = *(const float4*)(fc1W + ((size_t)g * 1536 + oc0 + r) * 384 + kc * 64 + c);
      w_s[r][c] = w.x; w_s[r][c+1] = w.y; w_s[r][c+2] = w.z; w_s[r][c+3] = w.w;
    }
    __syncthreads();
#pragma unroll 4
    for (int kk = 0; kk < 64; ++kk) {
      float yv0 = y_s[4*tyb+0][kk], yv1 = y_s[4*tyb+1][kk], yv2 = y_s[4*tyb+2][kk], yv3 = y_s[4*tyb+3][kk];
      float wv0 = w_s[4*txo+0][kk], wv1 = w_s[4*txo+1][kk], wv2 = w_s[4*txo+2][kk], wv3 = w_s[4*txo+3][kk];
      acc[0][0] += yv0*wv0; acc[0][1] += yv0*wv1; acc[0][2] += yv0*wv2; acc[0][3] += yv0*wv3;
      acc[1][0] += yv1*wv0; acc[1][1] += yv1*wv1; acc[1][2] += yv1*wv2; acc[1][3] += yv1*wv3;
      acc[2][0] += yv2*wv0; acc[2][1] += yv2*wv1; acc[2][2] += yv2*wv2; acc[2][3] += yv2*wv3;
      acc[3][0] += yv3*wv0; acc[3][1] += yv3*wv1; acc[3][2] += yv3*wv2; acc[3][3] += yv3*wv3;
    }
    __syncthreads();
  }

  float* H2 = ws + WS_H2;
#pragma unroll
  for (int i = 0; i < 4; ++i) {
    int bb = 4 * tyb + i;
#pragma unroll
    for (int j = 0; j < 4; ++j) {
      int oc = oc0 + 4 * txo + j;
      float v = acc[i][j] + fc1b[g * 1536 + oc];
      v = 0.5f * v * (1.f + erff(v * 0.70710678118654752f));
      // channel shuffle: h2[(oc&1)*1536 + g*768 + oc/2] = h[g*1536+oc]
      H2[(size_t)bb * HIDN + (oc & 1) * 1536 + g * 768 + (oc >> 1)] = v;
    }
  }
}

// ============================================================
// K4c: fc2 (grouped, k-split into 4 partials)
// ============================================================
__global__ __launch_bounds__(256) void k_fc2(
    const float* __restrict__ fc2W, float* __restrict__ ws)
{
  const int oc0 = blockIdx.x * 64;   // 0..5
  const int kq = blockIdx.y;          // 0..3
  const int g = blockIdx.z;           // 0..1
  const int t = threadIdx.x;
  const int txo = t & 15, tyb = t >> 4;

  __shared__ float h_s[64][65];
  __shared__ float w_s[64][65];

  float acc[4][4];
#pragma unroll
  for (int i = 0; i < 4; ++i)
#pragma unroll
    for (int j = 0; j < 4; ++j) acc[i][j] = 0.f;

  const float* H2 = ws + WS_H2;

#pragma unroll 1
  for (int kc = 0; kc < 6; ++kc) {
    int kbase = kq * 384 + kc * 64;
    int r = t >> 2;
    int cb = (t & 3) * 4;
#pragma unroll
    for (int p = 0; p < 4; ++p) {
      int c = cb + p * 16;
      float4 v = *(const float4*)(H2 + (size_t)r * HIDN + g * 1536 + kbase + c);
      h_s[r][c] = v.x; h_s[r][c+1] = v.y; h_s[r][c+2] = v.z; h_s[r][c+3] = v.w;
      float4 w = *(const float4*)(fc2W + ((size_t)g * 384 + oc0 + r) * 1536 + kbase + c);
      w_s[r][c] = w.x; w_s[r][c+1] = w.y; w_s[r][c+2] = w.z; w_s[r][c+3] = w.w;
    }
    __syncthreads();
#pragma unroll 4
    for (int kk = 0; kk < 64; ++kk) {
      float hv0 = h_s[4*tyb+0][kk], hv1 = h_s[4*tyb+1][kk], hv2 = h_s[4*tyb+2][kk], hv3 = h_s[4*tyb+3][kk];
      float wv0 = w_s[4*txo+0][kk], wv1 = w_s[4*txo+1][kk], wv2 = w_s[4*txo+2][kk], wv3 = w_s[4*txo+3][kk];
      acc[0][0] += hv0*wv0; acc[0][1] += hv0*wv1; acc[0][2] += hv0*wv2; acc[0][3] += hv0*wv3;
      acc[1][0] += hv1*wv0; acc[1][1] += hv1*wv1; acc[1][2] += hv1*wv2; acc[1][3] += hv1*wv3;
      acc[2][0] += hv2*wv0; acc[2][1] += hv2*wv1; acc[2][2] += hv2*wv2; acc[2][3] += hv2*wv3;
      acc[3][0] += hv3*wv0; acc[3][1] += hv3*wv1; acc[3][2] += hv3*wv2; acc[3][3] += hv3*wv3;
    }
    __syncthreads();
  }

  float* ZP = ws + WS_ZP + (size_t)kq * BB * DD;
#pragma unroll
  for (int i = 0; i < 4; ++i)
#pragma unroll
    for (int j = 0; j < 4; ++j)
      ZP[(size_t)(4 * tyb + i) * DD + g * 384 + oc0 + 4 * txo + j] = acc[i][j];
}

// ============================================================
// K4d: out_cls = c1 + fc2_b + sum of partials
// ============================================================
__global__ __launch_bounds__(256) void k_final(
    const float* __restrict__ fc2b, float* __restrict__ out, const float* __restrict__ ws)
{
  int idx = blockIdx.x * 256 + threadIdx.x;   // < 49152
  int d = idx % DD;                            // d = g*384+oc matches fc2b flat
  float v = ws[WS_C1 + idx] + fc2b[d];
#pragma unroll
  for (int kq = 0; kq < 4; ++kq) v += ws[WS_ZP + (size_t)kq * BB * DD + idx];
  out[idx] = v;
}

extern "C" void kernel_launch(void* const* d_in, const int* in_sizes, int n_in,
                              void* d_out, int out_size, void* d_ws, size_t ws_size,
                              hipStream_t stream)
{
  (void)in_sizes; (void)n_in; (void)out_size; (void)ws_size;
  const float* x_cls = (const float*)d_in[0];
  const float* x_img = (const float*)d_in[1];
  const float* ln1_g = (const float*)d_in[2];
  const float* ln1_b = (const float*)d_in[3];
  const float* Wq    = (const float*)d_in[4];
  const float* bq    = (const float*)d_in[5];
  const float* Wk    = (const float*)d_in[6];
  const float* bk    = (const float*)d_in[7];
  const float* Wv    = (const float*)d_in[8];
  const float* bv    = (const float*)d_in[9];
  const float* w1W   = (const float*)d_in[10];
  const float* w1b   = (const float*)d_in[11];
  const float* w2W   = (const float*)d_in[12];
  const float* w2b   = (const float*)d_in[13];
  const float* projW = (const float*)d_in[14];
  const float* projb = (const float*)d_in[15];
  const float* ln2_g = (const float*)d_in[16];
  const float* ln2_b = (const float*)d_in[17];
  const float* fc1W  = (const float*)d_in[18];
  const float* fc1b  = (const float*)d_in[19];
  const float* fc2W  = (const float*)d_in[20];
  const float* fc2b  = (const float*)d_in[21];
  float* out = (float*)d_out;
  float* ws  = (float*)d_ws;

  k_qprep<<<dim3(64), dim3(256), 0, stream>>>(x_cls, ln1_g, ln1_b, Wq, bq, Wk, bk, w1W, w1b, ws);
  k_main1<<<dim3(4, 64), dim3(256), 0, stream>>>(x_cls, x_img, out, ws);
  k_softmax<<<dim3(64), dim3(256), 0, stream>>>(w2W, w2b, ws);
  k_wsum<<<dim3(6, 64), dim3(128), 0, stream>>>(x_cls, x_img, ws);
  k_proj<<<dim3(64), dim3(256), 0, stream>>>(x_cls, ln1_g, ln1_b, Wv, bv, projW, projb, ln2_g, ln2_b, ws);
  k_fc1<<<dim3(48), dim3(256), 0, stream>>>(fc1W, fc1b, ws);
  k_fc2<<<dim3(6, 4, 2), dim3(256), 0, stream>>>(fc2W, ws);
  k_final<<<dim3(192), dim3(256), 0, stream>>>(fc2b, out, ws);
}

// Round 2
// 477.046 us; speedup vs baseline: 2.7302x; 2.7302x over previous
//
#include <hip/hip_runtime.h>
#include <math.h>

#define BB   64
#define NN   784
#define DD   768
#define HH   32
#define HD24 24
#define MM   785
#define HIDN 3072
#define QSCALE 0.20412414523193154f
#define LNEPS 1e-6f

// ---- workspace layout (float offsets) ----
// lifetimes: NC d1-d2, Q d2-d5, RS/RM d4-d5 -> ZP (d11-d12) overlays [0,196608)
#define WS_NC    0          // [64][768]
#define WS_Q     49152      // [64][768]
#define WS_RS    98304      // [64][785]
#define WS_RM    148544     // [64][785]
#define WS_ZP    0          // [4][64][768] (overlays NC/Q/RS/RM, all dead by d5)
#define WS_S1P   198784     // [64][6][32] partial s1
#define WS_BQP   211072     // [64][6][32] partial bqs
#define WS_A2    223360     // [64][32]
#define WS_WM    225408     // [64][32]
#define WS_C1    227456     // [64][768]
#define WS_Y     276608     // [64][768]
#define WS_H2    325760     // [64][3072]
#define WS_E     522368     // gqkT [64][768][32] (d3-d4) then E/W [64][32][800] (d5-d6) then o [64][768] (d7-d8)
#define WS_O     WS_E
#define WS_T     2160768    // t [64][785][32] (d4-d5) then r [64][32][768] (d6-d7)

// ============================================================
// d1: LN of cls rows -> nc
// ============================================================
__global__ __launch_bounds__(256) void k_lncls(
    const float* __restrict__ x_cls,
    const float* __restrict__ g1, const float* __restrict__ b1,
    float* __restrict__ ws)
{
  const int b = blockIdx.x;
  const int t = threadIdx.x;
  const int lane = t & 63, wid = t >> 6;
  __shared__ float redS[4], redQ[4];
  __shared__ float mu_sh, rs_sh;

  float xv[3];
  float s = 0.f, q2 = 0.f;
#pragma unroll
  for (int k = 0; k < 3; ++k) {
    float v = x_cls[(size_t)b * DD + t + 256 * k];
    xv[k] = v; s += v; q2 += v * v;
  }
#pragma unroll
  for (int off = 1; off < 64; off <<= 1) { s += __shfl_xor(s, off); q2 += __shfl_xor(q2, off); }
  if (lane == 0) { redS[wid] = s; redQ[wid] = q2; }
  __syncthreads();
  if (t == 0) {
    float ss = redS[0] + redS[1] + redS[2] + redS[3];
    float qq = redQ[0] + redQ[1] + redQ[2] + redQ[3];
    float mu = ss * (1.f / DD);
    mu_sh = mu; rs_sh = rsqrtf(qq * (1.f / DD) - mu * mu + LNEPS);
  }
  __syncthreads();
  float mu = mu_sh, rs = rs_sh;
#pragma unroll
  for (int k = 0; k < 3; ++k) {
    int d = t + 256 * k;
    ws[WS_NC + (size_t)b * DD + d] = (xv[k] - mu) * rs * g1[d] + b1[d];
  }
}

// ============================================================
// d2: q = (nc @ Wq + bq) * QSCALE    grid (12 octiles, 64 b)
// ============================================================
__global__ __launch_bounds__(256) void k_q(
    const float* __restrict__ Wq, const float* __restrict__ bq,
    float* __restrict__ ws)
{
  const int b = blockIdx.y;
  const int oc0 = blockIdx.x * 64;
  const int t = threadIdx.x;
  const int oc = t & 63, ks = t >> 6;

  __shared__ __align__(16) float nc_l[DD];
  __shared__ float red[4][64];

  for (int i = t; i < DD; i += 256) nc_l[i] = ws[WS_NC + (size_t)b * DD + i];
  __syncthreads();

  const float* wp = Wq + (size_t)(ks * 192) * DD + oc0 + oc;
  const float* ncp = nc_l + ks * 192;
  float a0 = 0.f, a1 = 0.f, a2 = 0.f, a3 = 0.f;
#pragma unroll 4
  for (int d = 0; d < 192; d += 4) {
    a0 += ncp[d + 0] * wp[(size_t)(d + 0) * DD];
    a1 += ncp[d + 1] * wp[(size_t)(d + 1) * DD];
    a2 += ncp[d + 2] * wp[(size_t)(d + 2) * DD];
    a3 += ncp[d + 3] * wp[(size_t)(d + 3) * DD];
  }
  red[ks][oc] = (a0 + a1) + (a2 + a3);
  __syncthreads();
  if (t < 64) {
    int ocg = oc0 + t;
    float q = (red[0][t] + red[1][t] + red[2][t] + red[3][t] + bq[ocg]) * QSCALE;
    ws[WS_Q + (size_t)b * DD + ocg] = q;
  }
}

// ============================================================
// d3: per (b, 128-d tile): qk[d][g] = Wk[d,g*24:]·q[g*24:], fold T1=I+w1,
// gqkT[b][d][h] = g1[d]*sum_g qk[g]T1[g][h]; partial s1, bqs.
// ============================================================
__global__ __launch_bounds__(256) void k_gqk(
    const float* __restrict__ g1, const float* __restrict__ b1,
    const float* __restrict__ Wk, const float* __restrict__ w1W,
    float* __restrict__ ws)
{
  const int b = blockIdx.y;
  const int d0 = blockIdx.x * 128;
  const int t = threadIdx.x;

  __shared__ __align__(16) float q_l[DD];
  __shared__ float T1[HH * HH];
  __shared__ float qk_l[128][33];
  __shared__ float pS[8][HH], pB[8][HH];

  for (int i = t; i < DD; i += 256) q_l[i] = ws[WS_Q + (size_t)b * DD + i];
  for (int i = t; i < HH * HH; i += 256) {
    int g = i >> 5, h = i & 31;
    T1[i] = w1W[i] + ((g == h) ? 1.f : 0.f);
  }
  __syncthreads();

  { // phase 1: qk
    const int dl = t >> 1, gh = t & 1;
    const float4* wr = (const float4*)(Wk + (size_t)(d0 + dl) * DD + gh * 384);
    const float4* qr = (const float4*)(q_l + gh * 384);
#pragma unroll 4
    for (int gg = 0; gg < 16; ++gg) {
      float a = 0.f;
#pragma unroll
      for (int c = 0; c < 6; ++c) {
        float4 w = wr[gg * 6 + c];
        float4 p = qr[gg * 6 + c];
        a += w.x * p.x + w.y * p.y + w.z * p.z + w.w * p.w;
      }
      qk_l[dl][gh * 16 + gg] = a;
    }
  }
  __syncthreads();
  { // phase 2: mix + partial sums
    const int h = t & 31, dg = t >> 5;
    float s1a = 0.f, bqa = 0.f;
    float* gout = ws + WS_E + ((size_t)b * DD + d0 + dg * 16) * HH + h;
#pragma unroll 2
    for (int dd = 0; dd < 16; ++dd) {
      int dl = dg * 16 + dd;
      float f = 0.f;
#pragma unroll 8
      for (int g = 0; g < HH; ++g) f += qk_l[dl][g] * T1[g * HH + h];
      float gq = g1[d0 + dl] * f;
      gout[(size_t)dd * HH] = gq;
      s1a += gq;
      bqa += b1[d0 + dl] * qk_l[dl][h];
    }
    pS[dg][h] = s1a; pB[dg][h] = bqa;
  }
  __syncthreads();
  if (t < HH) {
    float s = 0.f, bq = 0.f;
#pragma unroll
    for (int k = 0; k < 8; ++k) { s += pS[k][t]; bq += pB[k][t]; }
    ws[WS_S1P + ((size_t)b * 6 + blockIdx.x) * HH + t] = s;
    ws[WS_BQP + ((size_t)b * 6 + blockIdx.x) * HH + t] = bq;
  }
}

// ============================================================
// d4: big pass 1: stage u rows, copy x_img->out, LN stats per row,
// t[b][m][h] = sum_d u[m,d]*gqkT[d,h].
// ============================================================
__global__ __launch_bounds__(256) void k_main1(
    const float* __restrict__ x_cls, const float* __restrict__ x_img,
    float* __restrict__ out, float* __restrict__ ws)
{
  const int b = blockIdx.y;
  const int m0 = blockIdx.x * 256;
  const int t = threadIdx.x;
  const int tx = t & 3;
  const int ty = t >> 2;
  const int prow = t >> 3;
  const int pcol = (t & 7) * 4;

  __shared__ __align__(16) float u_lds[256][36];
  __shared__ __align__(16) float gq_lds[32][36];

  float* out_img = out + (size_t)BB * DD;
  const float* gq_src = ws + WS_E + (size_t)b * DD * HH;

  float acc[4][8];
#pragma unroll
  for (int i = 0; i < 4; ++i)
#pragma unroll
    for (int j = 0; j < 8; ++j) acc[i][j] = 0.f;
  float ssum = 0.f, ssq = 0.f;

  float4 pf[8];
  float4 pfg;

  auto k1_load = [&](int dc) {
#pragma unroll
    for (int kk = 0; kk < 8; ++kk) {
      int m = m0 + prow + 32 * kk;
      if (m < MM) {
        const float* src = (m == 0) ? (x_cls + (size_t)b * DD)
                                    : (x_img + ((size_t)b * NN + (m - 1)) * DD);
        pf[kk] = *(const float4*)(src + dc * 32 + pcol);
      } else {
        pf[kk] = make_float4(0.f, 0.f, 0.f, 0.f);
      }
    }
    pfg = *(const float4*)(gq_src + (size_t)(dc * 32 + prow) * HH + pcol);
  };
  auto k1_store = [&](int dc) {
#pragma unroll
    for (int kk = 0; kk < 8; ++kk) {
      int r = prow + 32 * kk;
      int m = m0 + r;
      *(float4*)&u_lds[r][pcol] = pf[kk];
      if (m >= 1 && m < MM)
        *(float4*)(out_img + ((size_t)b * NN + (m - 1)) * DD + dc * 32 + pcol) = pf[kk];
    }
    *(float4*)&gq_lds[prow][pcol] = pfg;
  };

  k1_load(0);
  k1_store(0);
  __syncthreads();

  for (int dc = 0; dc < 24; ++dc) {
    if (dc < 23) k1_load(dc + 1);
#pragma unroll 8
    for (int j = 0; j < 32; ++j) {
      float v = u_lds[t][(t + j) & 31];
      ssum += v; ssq += v * v;
    }
#pragma unroll 2
    for (int dd = 0; dd < 32; ++dd) {
      float4 g0 = *(const float4*)&gq_lds[dd][8 * tx];
      float4 g1v = *(const float4*)&gq_lds[dd][8 * tx + 4];
#pragma unroll
      for (int i = 0; i < 4; ++i) {
        float uv = u_lds[ty + 64 * i][dd];
        acc[i][0] += uv * g0.x; acc[i][1] += uv * g0.y;
        acc[i][2] += uv * g0.z; acc[i][3] += uv * g0.w;
        acc[i][4] += uv * g1v.x; acc[i][5] += uv * g1v.y;
        acc[i][6] += uv * g1v.z; acc[i][7] += uv * g1v.w;
      }
    }
    __syncthreads();
    if (dc < 23) k1_store(dc + 1);
    __syncthreads();
  }

  float* tmat = ws + WS_T;
#pragma unroll
  for (int i = 0; i < 4; ++i) {
    int m = m0 + ty + 64 * i;
    if (m < MM) {
      float* dst = tmat + ((size_t)b * MM + m) * HH + 8 * tx;
      *(float4*)dst = make_float4(acc[i][0], acc[i][1], acc[i][2], acc[i][3]);
      *(float4*)(dst + 4) = make_float4(acc[i][4], acc[i][5], acc[i][6], acc[i][7]);
    }
  }
  {
    int m = m0 + t;
    if (m < MM) {
      float mu = ssum * (1.f / DD);
      float var = ssq * (1.f / DD) - mu * mu;
      float rs = rsqrtf(var + LNEPS);
      ws[WS_RS + (size_t)b * MM + m] = rs;
      ws[WS_RM + (size_t)b * MM + m] = rs * mu;
    }
  }
}

// ============================================================
// d5: per-b: finalize s1/bqs/c0; softmax over m; post-mix; w/A2/WM.
// ============================================================
__global__ __launch_bounds__(256) void k_softmax(
    const float* __restrict__ bk,
    const float* __restrict__ w1W, const float* __restrict__ w1b,
    const float* __restrict__ w2W, const float* __restrict__ w2b,
    float* __restrict__ ws)
{
  const int b = blockIdx.x;
  const int t = threadIdx.x;
  const int lane = t & 63;
  const int wid = t >> 6;

  __shared__ float s1_sh[HH], c0_sh[HH], w2b_sh[HH], bq_sh[HH];
  __shared__ float T1[HH * HH];
  __shared__ float part[4][HH];
  __shared__ float mx_sh[HH], sum_sh[HH];
  __shared__ float T2p[HH * HH];

  for (int i = t; i < HH * HH; i += 256) {
    int g = i >> 5, h = i & 31;
    T1[i] = w1W[i] + ((g == h) ? 1.f : 0.f);
  }
  if (t < HH) {
    float s1v = 0.f, bqv = 0.f;
#pragma unroll
    for (int p = 0; p < 6; ++p) {
      s1v += ws[WS_S1P + ((size_t)b * 6 + p) * HH + t];
      bqv += ws[WS_BQP + ((size_t)b * 6 + p) * HH + t];
    }
    const float* qp = ws + WS_Q + (size_t)b * DD + t * HD24;
#pragma unroll
    for (int j = 0; j < HD24; ++j) bqv += bk[t * HD24 + j] * qp[j];
    s1_sh[t] = s1v; bq_sh[t] = bqv; w2b_sh[t] = w2b[t];
  }
  __syncthreads();
  if (t < HH) {
    float c0 = w1b[t];
#pragma unroll
    for (int g = 0; g < HH; ++g) c0 += T1[g * HH + t] * bq_sh[g];
    c0_sh[t] = c0;
  }
  __syncthreads();

  const float* tmat = ws + WS_T + (size_t)b * MM * HH;
  const float* rs_p = ws + WS_RS + (size_t)b * MM;
  const float* rm_p = ws + WS_RM + (size_t)b * MM;
  float* E = ws + WS_E + (size_t)b * HH * 800;

  float lv[HH];
#pragma unroll
  for (int h = 0; h < HH; ++h) lv[h] = -3.0e38f;
#pragma unroll 1
  for (int k = 0; k < 4; ++k) {
    int m = t + 256 * k;
    if (m < MM) {
      float rs = rs_p[m], rm = rm_p[m];
      const float4* tr = (const float4*)(tmat + (size_t)m * HH);
#pragma unroll
      for (int qq = 0; qq < 8; ++qq) {
        float4 tv = tr[qq];
        int h = qq * 4;
        lv[h+0] = fmaxf(lv[h+0], rs*tv.x - rm*s1_sh[h+0] + c0_sh[h+0]);
        lv[h+1] = fmaxf(lv[h+1], rs*tv.y - rm*s1_sh[h+1] + c0_sh[h+1]);
        lv[h+2] = fmaxf(lv[h+2], rs*tv.z - rm*s1_sh[h+2] + c0_sh[h+2]);
        lv[h+3] = fmaxf(lv[h+3], rs*tv.w - rm*s1_sh[h+3] + c0_sh[h+3]);
      }
    }
  }
#pragma unroll
  for (int h = 0; h < HH; ++h) {
    float v = lv[h];
#pragma unroll
    for (int off = 1; off < 64; off <<= 1) v = fmaxf(v, __shfl_xor(v, off));
    if (lane == 0) part[wid][h] = v;
  }
  __syncthreads();
  if (t < HH) mx_sh[t] = fmaxf(fmaxf(part[0][t], part[1][t]), fmaxf(part[2][t], part[3][t]));
  __syncthreads();

#pragma unroll
  for (int h = 0; h < HH; ++h) lv[h] = 0.f;
#pragma unroll 1
  for (int k = 0; k < 4; ++k) {
    int m = t + 256 * k;
    if (m < MM) {
      float rs = rs_p[m], rm = rm_p[m];
      const float4* tr = (const float4*)(tmat + (size_t)m * HH);
#pragma unroll
      for (int qq = 0; qq < 8; ++qq) {
        float4 tv = tr[qq];
        int h = qq * 4;
        float e0 = __expf(rs*tv.x - rm*s1_sh[h+0] + c0_sh[h+0] - mx_sh[h+0]);
        float e1 = __expf(rs*tv.y - rm*s1_sh[h+1] + c0_sh[h+1] - mx_sh[h+1]);
        float e2 = __expf(rs*tv.z - rm*s1_sh[h+2] + c0_sh[h+2] - mx_sh[h+2]);
        float e3 = __expf(rs*tv.w - rm*s1_sh[h+3] + c0_sh[h+3] - mx_sh[h+3]);
        lv[h+0] += e0; lv[h+1] += e1; lv[h+2] += e2; lv[h+3] += e3;
        E[(size_t)(h+0)*800 + m] = e0;
        E[(size_t)(h+1)*800 + m] = e1;
        E[(size_t)(h+2)*800 + m] = e2;
        E[(size_t)(h+3)*800 + m] = e3;
      }
    }
  }
#pragma unroll
  for (int h = 0; h < HH; ++h) {
    float v = lv[h];
#pragma unroll
    for (int off = 1; off < 64; off <<= 1) v += __shfl_xor(v, off);
    if (lane == 0) part[wid][h] = v;
  }
  __syncthreads();
  if (t < HH) sum_sh[t] = part[0][t] + part[1][t] + part[2][t] + part[3][t];
  __syncthreads();

  for (int i = t; i < HH * HH; i += 256) {
    int g = i >> 5, h = i & 31;
    T2p[i] = (w2W[i] + ((g == h) ? 1.f : 0.f)) / sum_sh[g];
  }
  __syncthreads();

  float A2l[HH], WMl[HH];
#pragma unroll
  for (int h = 0; h < HH; ++h) { A2l[h] = 0.f; WMl[h] = 0.f; }
#pragma unroll 1
  for (int k = 0; k < 4; ++k) {
    int m = t + 256 * k;
    if (m < 800) {
      if (m < MM) {
        float eg[HH];
#pragma unroll
        for (int g = 0; g < HH; ++g) eg[g] = E[(size_t)g * 800 + m];
        float rs = rs_p[m], rm = rm_p[m];
#pragma unroll
        for (int h = 0; h < HH; ++h) {
          float a2 = w2b_sh[h];
#pragma unroll
          for (int g = 0; g < HH; ++g) a2 += eg[g] * T2p[g * HH + h];
          A2l[h] += a2;
          WMl[h] += a2 * rm;
          E[(size_t)h * 800 + m] = a2 * rs;
        }
      } else {
#pragma unroll
        for (int h = 0; h < HH; ++h) E[(size_t)h * 800 + m] = 0.f;
      }
    }
  }
#pragma unroll
  for (int h = 0; h < HH; ++h) {
    float v = A2l[h];
#pragma unroll
    for (int off = 1; off < 64; off <<= 1) v += __shfl_xor(v, off);
    if (lane == 0) part[wid][h] = v;
  }
  __syncthreads();
  if (t < HH) ws[WS_A2 + b * HH + t] = part[0][t] + part[1][t] + part[2][t] + part[3][t];
  __syncthreads();
#pragma unroll
  for (int h = 0; h < HH; ++h) {
    float v = WMl[h];
#pragma unroll
    for (int off = 1; off < 64; off <<= 1) v += __shfl_xor(v, off);
    if (lane == 0) part[wid][h] = v;
  }
  __syncthreads();
  if (t < HH) ws[WS_WM + b * HH + t] = part[0][t] + part[1][t] + part[2][t] + part[3][t];
}

// ============================================================
// d6: r[b][h][d] = sum_m w[b][h][m] * u[b][m][d]
// ============================================================
__global__ __launch_bounds__(128) void k_wsum(
    const float* __restrict__ x_cls, const float* __restrict__ x_img,
    float* __restrict__ ws)
{
  const int b = blockIdx.y;
  const int d0 = blockIdx.x * 128;
  const int t = threadIdx.x;
  const int hg = t >> 4;
  const int dg = t & 15;

  __shared__ __align__(16) float u_s[32][132];
  __shared__ __align__(16) float w_s[32][36];

  const float* W = ws + WS_E + (size_t)b * HH * 800;

  float acc[4][8];
#pragma unroll
  for (int i = 0; i < 4; ++i)
#pragma unroll
    for (int j = 0; j < 8; ++j) acc[i][j] = 0.f;

  float4 pu[8];
  float4 pw[2];

  auto k3_load = [&](int mc) {
#pragma unroll
    for (int p = 0; p < 8; ++p) {
      int r = (t >> 5) + p * 4;
      int c = (t & 31) * 4;
      int m = mc * 32 + r;
      if (m < MM) {
        const float* src = (m == 0) ? (x_cls + (size_t)b * DD)
                                    : (x_img + ((size_t)b * NN + (m - 1)) * DD);
        pu[p] = *(const float4*)(src + d0 + c);
      } else pu[p] = make_float4(0.f, 0.f, 0.f, 0.f);
    }
    int h = t >> 2;
#pragma unroll
    for (int pp = 0; pp < 2; ++pp) {
      int c = (t & 3) * 4 + pp * 16;
      pw[pp] = *(const float4*)(W + (size_t)h * 800 + mc * 32 + c);
    }
  };
  auto k3_store = [&]() {
#pragma unroll
    for (int p = 0; p < 8; ++p) {
      int r = (t >> 5) + p * 4;
      int c = (t & 31) * 4;
      *(float4*)&u_s[r][c] = pu[p];
    }
    int h = t >> 2;
#pragma unroll
    for (int pp = 0; pp < 2; ++pp) {
      int c = (t & 3) * 4 + pp * 16;
      *(float4*)&w_s[h][c] = pw[pp];
    }
  };

  k3_load(0);
  k3_store();
  __syncthreads();

  for (int mc = 0; mc < 25; ++mc) {
    if (mc < 24) k3_load(mc + 1);
#pragma unroll 2
    for (int mm = 0; mm < 32; ++mm) {
      float4 u0 = *(const float4*)&u_s[mm][4 * dg];
      float4 u1 = *(const float4*)&u_s[mm][64 + 4 * dg];
      float w0 = w_s[4 * hg + 0][mm];
      float w1 = w_s[4 * hg + 1][mm];
      float w2 = w_s[4 * hg + 2][mm];
      float w3 = w_s[4 * hg + 3][mm];
      acc[0][0] += w0*u0.x; acc[0][1] += w0*u0.y; acc[0][2] += w0*u0.z; acc[0][3] += w0*u0.w;
      acc[0][4] += w0*u1.x; acc[0][5] += w0*u1.y; acc[0][6] += w0*u1.z; acc[0][7] += w0*u1.w;
      acc[1][0] += w1*u0.x; acc[1][1] += w1*u0.y; acc[1][2] += w1*u0.z; acc[1][3] += w1*u0.w;
      acc[1][4] += w1*u1.x; acc[1][5] += w1*u1.y; acc[1][6] += w1*u1.z; acc[1][7] += w1*u1.w;
      acc[2][0] += w2*u0.x; acc[2][1] += w2*u0.y; acc[2][2] += w2*u0.z; acc[2][3] += w2*u0.w;
      acc[2][4] += w2*u1.x; acc[2][5] += w2*u1.y; acc[2][6] += w2*u1.z; acc[2][7] += w2*u1.w;
      acc[3][0] += w3*u0.x; acc[3][1] += w3*u0.y; acc[3][2] += w3*u0.z; acc[3][3] += w3*u0.w;
      acc[3][4] += w3*u1.x; acc[3][5] += w3*u1.y; acc[3][6] += w3*u1.z; acc[3][7] += w3*u1.w;
    }
    __syncthreads();
    if (mc < 24) k3_store();
    __syncthreads();
  }

  float* R = ws + WS_T;
#pragma unroll
  for (int i = 0; i < 4; ++i) {
    int h = 4 * hg + i;
    float* dst = R + ((size_t)b * HH + h) * DD + d0;
    *(float4*)(dst + 4 * dg)      = make_float4(acc[i][0], acc[i][1], acc[i][2], acc[i][3]);
    *(float4*)(dst + 64 + 4 * dg) = make_float4(acc[i][4], acc[i][5], acc[i][6], acc[i][7]);
  }
}

// ============================================================
// d7: o[b][h*24+oc] = agg[b,h,:] @ Wv[:,h*24+oc] + A2*bv
//     agg = g1*(r - WM) + b1*A2.   grid (32 h, 64 b), block 192
// ============================================================
__global__ __launch_bounds__(192) void k_att_o(
    const float* __restrict__ g1, const float* __restrict__ b1,
    const float* __restrict__ Wv, const float* __restrict__ bv,
    float* __restrict__ ws)
{
  const int h = blockIdx.x;
  const int b = blockIdx.y;
  const int t = threadIdx.x;

  __shared__ __align__(16) float agg_l[DD];
  __shared__ float red[8][25];

  const float A2 = ws[WS_A2 + b * HH + h];
  const float WM = ws[WS_WM + b * HH + h];
  const float* R = ws + WS_T + ((size_t)b * HH + h) * DD;

  for (int i = t; i < DD; i += 192)
    agg_l[i] = g1[i] * (R[i] - WM) + b1[i] * A2;
  __syncthreads();

  const int oc = t % 24, ks = t / 24;
  const float* wv = Wv + (size_t)(ks * 96) * DD + h * HD24 + oc;
  const float* ag = agg_l + ks * 96;
  float a0 = 0.f, a1 = 0.f, a2 = 0.f, a3 = 0.f;
#pragma unroll 4
  for (int d = 0; d < 96; d += 4) {
    a0 += ag[d + 0] * wv[(size_t)(d + 0) * DD];
    a1 += ag[d + 1] * wv[(size_t)(d + 1) * DD];
    a2 += ag[d + 2] * wv[(size_t)(d + 2) * DD];
    a3 += ag[d + 3] * wv[(size_t)(d + 3) * DD];
  }
  red[ks][oc] = (a0 + a1) + (a2 + a3);
  __syncthreads();
  if (t < 24) {
    float o = A2 * bv[h * HD24 + t];
#pragma unroll
    for (int k = 0; k < 8; ++k) o += red[k][t];
    ws[WS_O + (size_t)b * DD + h * HD24 + t] = o;
  }
}

// ============================================================
// d8: c1 = x_cls + o @ projW + projb.   grid (12, 64)
// ============================================================
__global__ __launch_bounds__(256) void k_proj2(
    const float* __restrict__ x_cls,
    const float* __restrict__ projW, const float* __restrict__ projb,
    float* __restrict__ ws)
{
  const int b = blockIdx.y;
  const int oc0 = blockIdx.x * 64;
  const int t = threadIdx.x;
  const int oc = t & 63, ks = t >> 6;

  __shared__ __align__(16) float o_l[DD];
  __shared__ float red[4][64];

  for (int i = t; i < DD; i += 256) o_l[i] = ws[WS_O + (size_t)b * DD + i];
  __syncthreads();

  const float* wp = projW + (size_t)(ks * 192) * DD + oc0 + oc;
  const float* op = o_l + ks * 192;
  float a0 = 0.f, a1 = 0.f, a2 = 0.f, a3 = 0.f;
#pragma unroll 4
  for (int d = 0; d < 192; d += 4) {
    a0 += op[d + 0] * wp[(size_t)(d + 0) * DD];
    a1 += op[d + 1] * wp[(size_t)(d + 1) * DD];
    a2 += op[d + 2] * wp[(size_t)(d + 2) * DD];
    a3 += op[d + 3] * wp[(size_t)(d + 3) * DD];
  }
  red[ks][oc] = (a0 + a1) + (a2 + a3);
  __syncthreads();
  if (t < 64) {
    int ocg = oc0 + t;
    float c1 = red[0][t] + red[1][t] + red[2][t] + red[3][t]
             + projb[ocg] + x_cls[(size_t)b * DD + ocg];
    ws[WS_C1 + (size_t)b * DD + ocg] = c1;
  }
}

// ============================================================
// d9: LN2 of c1 -> y
// ============================================================
__global__ __launch_bounds__(256) void k_ln2(
    const float* __restrict__ g2, const float* __restrict__ b2,
    float* __restrict__ ws)
{
  const int b = blockIdx.x;
  const int t = threadIdx.x;
  const int lane = t & 63, wid = t >> 6;
  __shared__ float redS[4], redQ[4];
  __shared__ float mu_sh, rs_sh;

  float xv[3];
  float s = 0.f, q2 = 0.f;
#pragma unroll
  for (int k = 0; k < 3; ++k) {
    float v = ws[WS_C1 + (size_t)b * DD + t + 256 * k];
    xv[k] = v; s += v; q2 += v * v;
  }
#pragma unroll
  for (int off = 1; off < 64; off <<= 1) { s += __shfl_xor(s, off); q2 += __shfl_xor(q2, off); }
  if (lane == 0) { redS[wid] = s; redQ[wid] = q2; }
  __syncthreads();
  if (t == 0) {
    float ss = redS[0] + redS[1] + redS[2] + redS[3];
    float qq = redQ[0] + redQ[1] + redQ[2] + redQ[3];
    float mu = ss * (1.f / DD);
    mu_sh = mu; rs_sh = rsqrtf(qq * (1.f / DD) - mu * mu + LNEPS);
  }
  __syncthreads();
  float mu = mu_sh, rs = rs_sh;
#pragma unroll
  for (int k = 0; k < 3; ++k) {
    int d = t + 256 * k;
    ws[WS_Y + (size_t)b * DD + d] = (xv[k] - mu) * rs * g2[d] + b2[d];
  }
}

// ============================================================
// d10: fc1 (grouped) + exact GELU + channel shuffle -> H2
// ============================================================
__global__ __launch_bounds__(256) void k_fc1(
    const float* __restrict__ fc1W, const float* __restrict__ fc1b,
    float* __restrict__ ws)
{
  const int g = blockIdx.x / 24;
  const int oc0 = (blockIdx.x % 24) * 64;
  const int t = threadIdx.x;
  const int txo = t & 15, tyb = t >> 4;

  __shared__ float y_s[64][65];
  __shared__ float w_s[64][65];

  float acc[4][4];
#pragma unroll
  for (int i = 0; i < 4; ++i)
#pragma unroll
    for (int j = 0; j < 4; ++j) acc[i][j] = 0.f;

  const float* Y = ws + WS_Y;

#pragma unroll 1
  for (int kc = 0; kc < 6; ++kc) {
    int r = t >> 2;
    int cb = (t & 3) * 4;
#pragma unroll
    for (int p = 0; p < 4; ++p) {
      int c = cb + p * 16;
      float4 v = *(const float4*)(Y + (size_t)r * DD + g * 384 + kc * 64 + c);
      y_s[r][c] = v.x; y_s[r][c+1] = v.y; y_s[r][c+2] = v.z; y_s[r][c+3] = v.w;
      float4 w = *(const float4*)(fc1W + ((size_t)g * 1536 + oc0 + r) * 384 + kc * 64 + c);
      w_s[r][c] = w.x; w_s[r][c+1] = w.y; w_s[r][c+2] = w.z; w_s[r][c+3] = w.w;
    }
    __syncthreads();
#pragma unroll 4
    for (int kk = 0; kk < 64; ++kk) {
      float yv0 = y_s[4*tyb+0][kk], yv1 = y_s[4*tyb+1][kk], yv2 = y_s[4*tyb+2][kk], yv3 = y_s[4*tyb+3][kk];
      float wv0 = w_s[4*txo+0][kk], wv1 = w_s[4*txo+1][kk], wv2 = w_s[4*txo+2][kk], wv3 = w_s[4*txo+3][kk];
      acc[0][0] += yv0*wv0; acc[0][1] += yv0*wv1; acc[0][2] += yv0*wv2; acc[0][3] += yv0*wv3;
      acc[1][0] += yv1*wv0; acc[1][1] += yv1*wv1; acc[1][2] += yv1*wv2; acc[1][3] += yv1*wv3;
      acc[2][0] += yv2*wv0; acc[2][1] += yv2*wv1; acc[2][2] += yv2*wv2; acc[2][3] += yv2*wv3;
      acc[3][0] += yv3*wv0; acc[3][1] += yv3*wv1; acc[3][2] += yv3*wv2; acc[3][3] += yv3*wv3;
    }
    __syncthreads();
  }

  float* H2 = ws + WS_H2;
#pragma unroll
  for (int i = 0; i < 4; ++i) {
    int bb = 4 * tyb + i;
#pragma unroll
    for (int j = 0; j < 4; ++j) {
      int oc = oc0 + 4 * txo + j;
      float v = acc[i][j] + fc1b[g * 1536 + oc];
      v = 0.5f * v * (1.f + erff(v * 0.70710678118654752f));
      H2[(size_t)bb * HIDN + (oc & 1) * 1536 + g * 768 + (oc >> 1)] = v;
    }
  }
}

// ============================================================
// d11: fc2 (grouped, k-split into 4 partials)
// ============================================================
__global__ __launch_bounds__(256) void k_fc2(
    const float* __restrict__ fc2W, float* __restrict__ ws)
{
  const int oc0 = blockIdx.x * 64;
  const int kq = blockIdx.y;
  const int g = blockIdx.z;
  const int t = threadIdx.x;
  const int txo = t & 15, tyb = t >> 4;

  __shared__ float h_s[64][65];
  __shared__ float w_s[64][65];

  float acc[4][4];
#pragma unroll
  for (int i = 0; i < 4; ++i)
#pragma unroll
    for (int j = 0; j < 4; ++j) acc[i][j] = 0.f;

  const float* H2 = ws + WS_H2;

#pragma unroll 1
  for (int kc = 0; kc < 6; ++kc) {
    int kbase = kq * 384 + kc * 64;
    int r = t >> 2;
    int cb = (t & 3) * 4;
#pragma unroll
    for (int p = 0; p < 4; ++p) {
      int c = cb + p * 16;
      float4 v = *(const float4*)(H2 + (size_t)r * HIDN + g * 1536 + kbase + c);
      h_s[r][c] = v.x; h_s[r][c+1] = v.y; h_s[r][c+2] = v.z; h_s[r][c+3] = v.w;
      float4 w = *(const float4*)(fc2W + ((size_t)g * 384 + oc0 + r) * 1536 + kbase + c);
      w_s[r][c] = w.x; w_s[r][c+1] = w.y; w_s[r][c+2] = w.z; w_s[r][c+3] = w.w;
    }
    __syncthreads();
#pragma unroll 4
    for (int kk = 0; kk < 64; ++kk) {
      float hv0 = h_s[4*tyb+0][kk], hv1 = h_s[4*tyb+1][kk], hv2 = h_s[4*tyb+2][kk], hv3 = h_s[4*tyb+3][kk];
      float wv0 = w_s[4*txo+0][kk], wv1 = w_s[4*txo+1][kk], wv2 = w_s[4*txo+2][kk], wv3 = w_s[4*txo+3][kk];
      acc[0][0] += hv0*wv0; acc[0][1] += hv0*wv1; acc[0][2] += hv0*wv2; acc[0][3] += hv0*wv3;
      acc[1][0] += hv1*wv0; acc[1][1] += hv1*wv1; acc[1][2] += hv1*wv2; acc[1][3] += hv1*wv3;
      acc[2][0] += hv2*wv0; acc[2][1] += hv2*wv1; acc[2][2] += hv2*wv2; acc[2][3] += hv2*wv3;
      acc[3][0] += hv3*wv0; acc[3][1] += hv3*wv1; acc[3][2] += hv3*wv2; acc[3][3] += hv3*wv3;
    }
    __syncthreads();
  }

  float* ZP = ws + WS_ZP + (size_t)kq * BB * DD;
#pragma unroll
  for (int i = 0; i < 4; ++i)
#pragma unroll
    for (int j = 0; j < 4; ++j)
      ZP[(size_t)(4 * tyb + i) * DD + g * 384 + oc0 + 4 * txo + j] = acc[i][j];
}

// ============================================================
// d12: out_cls = c1 + fc2_b + sum of partials
// ============================================================
__global__ __launch_bounds__(256) void k_final(
    const float* __restrict__ fc2b, float* __restrict__ out, const float* __restrict__ ws)
{
  int idx = blockIdx.x * 256 + threadIdx.x;
  int d = idx % DD;
  float v = ws[WS_C1 + idx] + fc2b[d];
#pragma unroll
  for (int kq = 0; kq < 4; ++kq) v += ws[WS_ZP + (size_t)kq * BB * DD + idx];
  out[idx] = v;
}

extern "C" void kernel_launch(void* const* d_in, const int* in_sizes, int n_in,
                              void* d_out, int out_size, void* d_ws, size_t ws_size,
                              hipStream_t stream)
{
  (void)in_sizes; (void)n_in; (void)out_size; (void)ws_size;
  const float* x_cls = (const float*)d_in[0];
  const float* x_img = (const float*)d_in[1];
  const float* ln1_g = (const float*)d_in[2];
  const float* ln1_b = (const float*)d_in[3];
  const float* Wq    = (const float*)d_in[4];
  const float* bq    = (const float*)d_in[5];
  const float* Wk    = (const float*)d_in[6];
  const float* bk    = (const float*)d_in[7];
  const float* Wv    = (const float*)d_in[8];
  const float* bv    = (const float*)d_in[9];
  const float* w1W   = (const float*)d_in[10];
  const float* w1b   = (const float*)d_in[11];
  const float* w2W   = (const float*)d_in[12];
  const float* w2b   = (const float*)d_in[13];
  const float* projW = (const float*)d_in[14];
  const float* projb = (const float*)d_in[15];
  const float* ln2_g = (const float*)d_in[16];
  const float* ln2_b = (const float*)d_in[17];
  const float* fc1W  = (const float*)d_in[18];
  const float* fc1b  = (const float*)d_in[19];
  const float* fc2W  = (const float*)d_in[20];
  const float* fc2b  = (const float*)d_in[21];
  float* out = (float*)d_out;
  float* ws  = (float*)d_ws;

  k_lncls<<<dim3(64), dim3(256), 0, stream>>>(x_cls, ln1_g, ln1_b, ws);
  k_q<<<dim3(12, 64), dim3(256), 0, stream>>>(Wq, bq, ws);
  k_gqk<<<dim3(6, 64), dim3(256), 0, stream>>>(ln1_g, ln1_b, Wk, w1W, ws);
  k_main1<<<dim3(4, 64), dim3(256), 0, stream>>>(x_cls, x_img, out, ws);
  k_softmax<<<dim3(64), dim3(256), 0, stream>>>(bk, w1W, w1b, w2W, w2b, ws);
  k_wsum<<<dim3(6, 64), dim3(128), 0, stream>>>(x_cls, x_img, ws);
  k_att_o<<<dim3(32, 64), dim3(192), 0, stream>>>(ln1_g, ln1_b, Wv, bv, ws);
  k_proj2<<<dim3(12, 64), dim3(256), 0, stream>>>(x_cls, projW, projb, ws);
  k_ln2<<<dim3(64), dim3(256), 0, stream>>>(ln2_g, ln2_b, ws);
  k_fc1<<<dim3(48), dim3(256), 0, stream>>>(fc1W, fc1b, ws);
  k_fc2<<<dim3(6, 4, 2), dim3(256), 0, stream>>>(fc2W, ws);
  k_final<<<dim3(192), dim3(256), 0, stream>>>(fc2b, out, ws);
}

// Round 3
// 335.705 us; speedup vs baseline: 3.8796x; 1.4210x over previous
//
#include <hip/hip_runtime.h>
#include <hip/hip_bf16.h>
#include <math.h>

#define BB   64
#define NN   784
#define DD   768
#define HH   32
#define HD24 24
#define MM   785
#define HIDN 3072
#define QSCALE 0.20412414523193154f
#define LNEPS 1e-6f

// ---- workspace layout (float offsets) ----
#define WS_Q     0          // [64][768]   d1..d4 (k_sm_a reads for bqs)
#define WS_RS    49152      // [64][800]   d3..d5
#define WS_RM    100352     // [64][800]
#define WS_S1P   151552     // [64][6][32]
#define WS_BQP   163840     // [64][6][32]
#define WS_LMX   176128     // [64][4][32]
#define WS_LSM   184320
#define WS_A2P   192512
#define WS_WMP   200704
#define WS_PS    208896     // [64][12][2]
#define WS_C1    210432     // [64][768]
#define WS_H2    259584     // [64][3072]
#define WS_O     456192     // [64][768]
#define WS_E     505344     // gqT [64][32][768] (d2-d3), then E/W [64][32][800] (d4-d6)
#define WS_T     2143744    // t [64][785][32] (d3-d4), then r [64][32][768] (d6-d7)
#define WS_ZP    0          // [4][64][768] overlay (d10-d11); everything under 196608 dead by then

__device__ __forceinline__ unsigned packbf(float a, float b) {
  union { __hip_bfloat162 h2; unsigned u; } cv;
  cv.h2 = __float22bfloat162_rn(make_float2(a, b));
  return cv.u;
}
__device__ __forceinline__ float lo16(unsigned w) { return __uint_as_float(w << 16); }
__device__ __forceinline__ float hi16(unsigned w) { return __uint_as_float(w & 0xffff0000u); }

// ============================================================
// d1: q = (LN(x_cls) @ Wq + bq) * QSCALE     grid (12, 64)
// ============================================================
__global__ __launch_bounds__(256) void k_q(
    const float* __restrict__ x_cls,
    const float* __restrict__ g1, const float* __restrict__ b1,
    const float* __restrict__ Wq, const float* __restrict__ bq,
    float* __restrict__ ws)
{
  const int b = blockIdx.y;
  const int oc0 = blockIdx.x * 64;
  const int t = threadIdx.x;
  const int lane = t & 63, wid = t >> 6;

  __shared__ __align__(16) float nc_l[DD];
  __shared__ float red4[4][64];
  __shared__ float rS[4], rQ[4];
  __shared__ float musd[2];

  float xv[3];
  float s = 0.f, q2 = 0.f;
#pragma unroll
  for (int k = 0; k < 3; ++k) {
    float v = x_cls[(size_t)b * DD + t + 256 * k];
    xv[k] = v; s += v; q2 += v * v;
  }
#pragma unroll
  for (int off = 1; off < 64; off <<= 1) { s += __shfl_xor(s, off); q2 += __shfl_xor(q2, off); }
  if (lane == 0) { rS[wid] = s; rQ[wid] = q2; }
  __syncthreads();
  if (t == 0) {
    float ss = rS[0] + rS[1] + rS[2] + rS[3];
    float qq = rQ[0] + rQ[1] + rQ[2] + rQ[3];
    float mu = ss * (1.f / DD);
    musd[0] = mu; musd[1] = rsqrtf(qq * (1.f / DD) - mu * mu + LNEPS);
  }
  __syncthreads();
  {
    float mu = musd[0], rs = musd[1];
#pragma unroll
    for (int k = 0; k < 3; ++k) {
      int d = t + 256 * k;
      nc_l[d] = (xv[k] - mu) * rs * g1[d] + b1[d];
    }
  }
  __syncthreads();

  const int oc = t & 63, ks = t >> 6;
  const float* wp = Wq + (size_t)(ks * 192) * DD + oc0 + oc;
  const float* ncp = nc_l + ks * 192;
  float a0 = 0.f, a1 = 0.f, a2 = 0.f, a3 = 0.f;
#pragma unroll 4
  for (int d = 0; d < 192; d += 4) {
    a0 += ncp[d + 0] * wp[(size_t)(d + 0) * DD];
    a1 += ncp[d + 1] * wp[(size_t)(d + 1) * DD];
    a2 += ncp[d + 2] * wp[(size_t)(d + 2) * DD];
    a3 += ncp[d + 3] * wp[(size_t)(d + 3) * DD];
  }
  red4[ks][oc] = (a0 + a1) + (a2 + a3);
  __syncthreads();
  if (t < 64) {
    int ocg = oc0 + t;
    ws[WS_Q + (size_t)b * DD + ocg] =
        (red4[0][t] + red4[1][t] + red4[2][t] + red4[3][t] + bq[ocg]) * QSCALE;
  }
}

// ============================================================
// d2: gqT[b][h][d] = g1[d]*sum_g qk[d][g]T1[g][h];  partial s1, bqs
// grid (6 d-tiles of 128, 64)
// ============================================================
__global__ __launch_bounds__(256) void k_gqk(
    const float* __restrict__ g1, const float* __restrict__ b1,
    const float* __restrict__ Wk, const float* __restrict__ w1W,
    float* __restrict__ ws)
{
  const int b = blockIdx.y;
  const int d0 = blockIdx.x * 128;
  const int t = threadIdx.x;

  __shared__ __align__(16) float q_l[DD];
  __shared__ float T1[HH * HH];
  __shared__ float qk_l[128][33];
  __shared__ float pS[8][HH], pB[8][HH];

  for (int i = t; i < DD; i += 256) q_l[i] = ws[WS_Q + (size_t)b * DD + i];
  for (int i = t; i < HH * HH; i += 256) {
    int g = i >> 5, h = i & 31;
    T1[i] = w1W[i] + ((g == h) ? 1.f : 0.f);
  }
  __syncthreads();

  { // phase 1: qk[d][g] (24-long head dots)
    const int dl = t >> 1, gh = t & 1;
    const float4* wr = (const float4*)(Wk + (size_t)(d0 + dl) * DD + gh * 384);
    const float4* qr = (const float4*)(q_l + gh * 384);
#pragma unroll 4
    for (int gg = 0; gg < 16; ++gg) {
      float a = 0.f;
#pragma unroll
      for (int c = 0; c < 6; ++c) {
        float4 w = wr[gg * 6 + c];
        float4 p = qr[gg * 6 + c];
        a += w.x * p.x + w.y * p.y + w.z * p.z + w.w * p.w;
      }
      qk_l[dl][gh * 16 + gg] = a;
    }
  }
  __syncthreads();
  { // phase 2: mix + write gqT[h][d] + partials
    const int h = t & 31, dg = t >> 5;
    float fb[16];
    float s1a = 0.f, bqa = 0.f;
#pragma unroll 2
    for (int dd = 0; dd < 16; ++dd) {
      int dl = dg * 16 + dd;
      float f = 0.f;
#pragma unroll 8
      for (int g = 0; g < HH; ++g) f += qk_l[dl][g] * T1[g * HH + h];
      float gq = g1[d0 + dl] * f;
      fb[dd] = gq;
      s1a += gq;
      bqa += b1[d0 + dl] * qk_l[dl][h];
    }
    float* gout = ws + WS_E + ((size_t)b * HH + h) * DD + d0 + dg * 16;
#pragma unroll
    for (int k = 0; k < 4; ++k)
      *(float4*)(gout + k * 4) = make_float4(fb[4*k], fb[4*k+1], fb[4*k+2], fb[4*k+3]);
    pS[dg][h] = s1a; pB[dg][h] = bqa;
  }
  __syncthreads();
  if (t < HH) {
    float s = 0.f, bq = 0.f;
#pragma unroll
    for (int k = 0; k < 8; ++k) { s += pS[k][t]; bq += pB[k][t]; }
    ws[WS_S1P + ((size_t)b * 6 + blockIdx.x) * HH + t] = s;
    ws[WS_BQP + ((size_t)b * 6 + blockIdx.x) * HH + t] = bq;
  }
}

// ============================================================
// d3: big pass 1. 64-row tiles, grid (13, 64).
// u->regs (stats + copy-out exact fp32); u->LDS as bf16 transposed;
// gq broadcast from LDS; 8m x 8h reg tile, 8-way d-split + shfl reduce.
// ============================================================
__global__ __launch_bounds__(256) void k_main1(
    const float* __restrict__ x_cls, const float* __restrict__ x_img,
    float* __restrict__ out, float* __restrict__ ws)
{
  const int b = blockIdx.y;
  const int m0 = blockIdx.x * 64;
  const int t = threadIdx.x;
  const int rp = t >> 3;          // 0..31 (row-pair, also gq-stage h)
  const int pc = (t & 7) * 4;     // col-in-chunk
  const int mo = t & 7;           // m-octet (compute)
  const int dsub = (t >> 3) & 7;  // d-subset (compute, in-wave)
  const int th = t >> 6;          // h-octet = wave id

  __shared__ unsigned uT[32][36];                 // [d-in-chunk][m-pair] bf16x2
  __shared__ __align__(16) float gqT[32][36];     // [h][d-in-chunk]

  const float* gq_src = ws + WS_E + (size_t)b * (HH * DD);
  float* out_img = out + (size_t)BB * DD;

  const int ma = m0 + 2 * rp;
  const int mb = ma + 1;
  const bool va = (ma < MM), vb = (mb < MM);
  const float* rowA = (ma == 0) ? (x_cls + (size_t)b * DD)
                                : (x_img + ((size_t)b * NN + (ma - 1)) * DD);
  const float* rowB = x_img + ((size_t)b * NN + (mb - 1)) * DD;
  float* orowA = out_img + ((size_t)b * NN + (ma - 1)) * DD;
  float* orowB = out_img + ((size_t)b * NN + (mb - 1)) * DD;

  float4 pf0, pf1, pfg;
  float sl0 = 0.f, sq0 = 0.f, sl1 = 0.f, sq1 = 0.f;

  auto LOADX = [&](int dc) {
    pf0 = va ? *(const float4*)(rowA + dc * 32 + pc) : make_float4(0.f,0.f,0.f,0.f);
    pf1 = vb ? *(const float4*)(rowB + dc * 32 + pc) : make_float4(0.f,0.f,0.f,0.f);
    sl0 += pf0.x + pf0.y + pf0.z + pf0.w;
    sq0 += pf0.x*pf0.x + pf0.y*pf0.y + pf0.z*pf0.z + pf0.w*pf0.w;
    sl1 += pf1.x + pf1.y + pf1.z + pf1.w;
    sq1 += pf1.x*pf1.x + pf1.y*pf1.y + pf1.z*pf1.z + pf1.w*pf1.w;
    pfg = *(const float4*)(gq_src + (size_t)rp * DD + dc * 32 + pc);
  };
  auto STOREX = [&](int dc) {
    if (va && ma >= 1) *(float4*)(orowA + dc * 32 + pc) = pf0;
    if (vb)            *(float4*)(orowB + dc * 32 + pc) = pf1;
    uT[pc + 0][rp] = packbf(pf0.x, pf1.x);
    uT[pc + 1][rp] = packbf(pf0.y, pf1.y);
    uT[pc + 2][rp] = packbf(pf0.z, pf1.z);
    uT[pc + 3][rp] = packbf(pf0.w, pf1.w);
    *(float4*)&gqT[rp][pc] = pfg;
  };

  float acc[8][8];
#pragma unroll
  for (int i = 0; i < 8; ++i)
#pragma unroll
    for (int j = 0; j < 8; ++j) acc[i][j] = 0.f;

  LOADX(0); STOREX(0); __syncthreads();

#define K1_DD2(COMP, DD2LIT)                                            \
  {                                                                     \
    uint4 uw = *(const uint4*)&uT[dsub * 4 + DD2LIT][mo * 4];           \
    float um0 = lo16(uw.x), um1 = hi16(uw.x);                           \
    float um2 = lo16(uw.y), um3 = hi16(uw.y);                           \
    float um4 = lo16(uw.z), um5 = hi16(uw.z);                           \
    float um6 = lo16(uw.w), um7 = hi16(uw.w);                           \
    _Pragma("unroll")                                                   \
    for (int j = 0; j < 8; ++j) {                                       \
      const float g = gq4[j].COMP;                                      \
      acc[0][j] += um0 * g; acc[1][j] += um1 * g;                       \
      acc[2][j] += um2 * g; acc[3][j] += um3 * g;                       \
      acc[4][j] += um4 * g; acc[5][j] += um5 * g;                       \
      acc[6][j] += um6 * g; acc[7][j] += um7 * g;                       \
    }                                                                   \
  }

  for (int dc = 0; dc < 24; ++dc) {
    if (dc < 23) LOADX(dc + 1);
    float4 gq4[8];
#pragma unroll
    for (int j = 0; j < 8; ++j) gq4[j] = *(const float4*)&gqT[th * 8 + j][dsub * 4];
    K1_DD2(x, 0)
    K1_DD2(y, 1)
    K1_DD2(z, 2)
    K1_DD2(w, 3)
    __syncthreads();
    if (dc < 23) STOREX(dc + 1);
    __syncthreads();
  }
#undef K1_DD2

  // reduce partial t over dsub (in-wave lanes 8,16,32 apart)
#pragma unroll
  for (int i = 0; i < 8; ++i)
#pragma unroll
    for (int j = 0; j < 8; ++j) {
      float v = acc[i][j];
      v += __shfl_xor(v, 8);
      v += __shfl_xor(v, 16);
      v += __shfl_xor(v, 32);
      acc[i][j] = v;
    }
  if (dsub == 0) {
    float* tb = ws + WS_T + (size_t)b * MM * HH;
#pragma unroll
    for (int i = 0; i < 8; ++i) {
      int m = m0 + mo * 8 + i;
      if (m < MM) {
        float* dst = tb + (size_t)m * HH + th * 8;
        *(float4*)dst = make_float4(acc[i][0], acc[i][1], acc[i][2], acc[i][3]);
        *(float4*)(dst + 4) = make_float4(acc[i][4], acc[i][5], acc[i][6], acc[i][7]);
      }
    }
  }
  // stats reduce over the 8 col-owner lanes (xor 1,2,4)
#pragma unroll
  for (int off = 1; off < 8; off <<= 1) {
    sl0 += __shfl_xor(sl0, off); sq0 += __shfl_xor(sq0, off);
    sl1 += __shfl_xor(sl1, off); sq1 += __shfl_xor(sq1, off);
  }
  if ((t & 7) == 0) {
    if (va) {
      float mu = sl0 * (1.f / DD);
      float rs = rsqrtf(sq0 * (1.f / DD) - mu * mu + LNEPS);
      ws[WS_RS + (size_t)b * 800 + ma] = rs;
      ws[WS_RM + (size_t)b * 800 + ma] = rs * mu;
    }
    if (vb) {
      float mu = sl1 * (1.f / DD);
      float rs = rsqrtf(sq1 * (1.f / DD) - mu * mu + LNEPS);
      ws[WS_RS + (size_t)b * 800 + mb] = rs;
      ws[WS_RM + (size_t)b * 800 + mb] = rs * mu;
    }
  }
}

// ============================================================
// d4: online softmax pass A. grid (4 m-chunks, 64). attn1 -> e, local max/sum.
// ============================================================
__global__ __launch_bounds__(256) void k_sm_a(
    const float* __restrict__ bk,
    const float* __restrict__ w1W, const float* __restrict__ w1b,
    float* __restrict__ ws)
{
  const int cx = blockIdx.x, b = blockIdx.y;
  const int t = threadIdx.x;
  const int lane = t & 63, wid = t >> 6;

  __shared__ float T1[HH * HH];
  __shared__ float s1_sh[HH], c0_sh[HH], bq_sh[HH];
  __shared__ float red[4][HH];
  __shared__ float lmax_sh[HH];

  for (int i = t; i < HH * HH; i += 256) {
    int g = i >> 5, h = i & 31;
    T1[i] = w1W[i] + ((g == h) ? 1.f : 0.f);
  }
  if (t < HH) {
    float s1v = 0.f, bqv = 0.f;
#pragma unroll
    for (int p = 0; p < 6; ++p) {
      s1v += ws[WS_S1P + ((size_t)b * 6 + p) * HH + t];
      bqv += ws[WS_BQP + ((size_t)b * 6 + p) * HH + t];
    }
    const float* qp = ws + WS_Q + (size_t)b * DD + t * HD24;
#pragma unroll
    for (int j = 0; j < HD24; ++j) bqv += bk[t * HD24 + j] * qp[j];
    s1_sh[t] = s1v; bq_sh[t] = bqv;
  }
  __syncthreads();
  if (t < HH) {
    float c0 = w1b[t];
#pragma unroll
    for (int g = 0; g < HH; ++g) c0 += T1[g * HH + t] * bq_sh[g];
    c0_sh[t] = c0;
  }
  __syncthreads();

  const int m = cx * 256 + t;
  const bool vm = (m < MM);
  float a1[HH];
  if (vm) {
    const float* tb = ws + WS_T + ((size_t)b * MM + m) * HH;
    float rs = ws[WS_RS + (size_t)b * 800 + m];
    float rm = ws[WS_RM + (size_t)b * 800 + m];
#pragma unroll
    for (int q = 0; q < 8; ++q) {
      float4 tv = *(const float4*)(tb + q * 4);
      a1[4*q+0] = rs * tv.x - rm * s1_sh[4*q+0] + c0_sh[4*q+0];
      a1[4*q+1] = rs * tv.y - rm * s1_sh[4*q+1] + c0_sh[4*q+1];
      a1[4*q+2] = rs * tv.z - rm * s1_sh[4*q+2] + c0_sh[4*q+2];
      a1[4*q+3] = rs * tv.w - rm * s1_sh[4*q+3] + c0_sh[4*q+3];
    }
  } else {
#pragma unroll
    for (int h = 0; h < HH; ++h) a1[h] = -3.0e38f;
  }
#pragma unroll
  for (int h = 0; h < HH; ++h) {
    float v = a1[h];
#pragma unroll
    for (int off = 1; off < 64; off <<= 1) v = fmaxf(v, __shfl_xor(v, off));
    if (lane == 0) red[wid][h] = v;
  }
  __syncthreads();
  if (t < HH) {
    float v = fmaxf(fmaxf(red[0][t], red[1][t]), fmaxf(red[2][t], red[3][t]));
    lmax_sh[t] = v;
    ws[WS_LMX + ((size_t)b * 4 + cx) * HH + t] = v;
  }
  __syncthreads();
  float* E = ws + WS_E + (size_t)b * (HH * 800);
  if (vm) {
#pragma unroll
    for (int h = 0; h < HH; ++h) {
      float e = __expf(a1[h] - lmax_sh[h]);
      a1[h] = e;
      E[(size_t)h * 800 + m] = e;
    }
  } else {
#pragma unroll
    for (int h = 0; h < HH; ++h) a1[h] = 0.f;
  }
#pragma unroll
  for (int h = 0; h < HH; ++h) {
    float v = a1[h];
#pragma unroll
    for (int off = 1; off < 64; off <<= 1) v += __shfl_xor(v, off);
    if (lane == 0) red[wid][h] = v;
  }
  __syncthreads();
  if (t < HH)
    ws[WS_LSM + ((size_t)b * 4 + cx) * HH + t] = red[0][t] + red[1][t] + red[2][t] + red[3][t];
}

// ============================================================
// d5: softmax pass B: finalize, post-mix (I+w2)/sum, w = a2*rs into W (=E),
// partial A2/WM. grid (4, 64).
// ============================================================
__global__ __launch_bounds__(256) void k_sm_b(
    const float* __restrict__ w2W, const float* __restrict__ w2b,
    float* __restrict__ ws)
{
  const int cx = blockIdx.x, b = blockIdx.y;
  const int t = threadIdx.x;
  const int lane = t & 63, wid = t >> 6;

  __shared__ __align__(16) float T2s[HH * HH];
  __shared__ float inv_sh[HH], w2b_sh[HH];
  __shared__ float red[4][HH];

  if (t < HH) {
    float l0 = ws[WS_LMX + ((size_t)b * 4 + 0) * HH + t];
    float l1 = ws[WS_LMX + ((size_t)b * 4 + 1) * HH + t];
    float l2 = ws[WS_LMX + ((size_t)b * 4 + 2) * HH + t];
    float l3 = ws[WS_LMX + ((size_t)b * 4 + 3) * HH + t];
    float gmax = fmaxf(fmaxf(l0, l1), fmaxf(l2, l3));
    float s = ws[WS_LSM + ((size_t)b * 4 + 0) * HH + t] * __expf(l0 - gmax)
            + ws[WS_LSM + ((size_t)b * 4 + 1) * HH + t] * __expf(l1 - gmax)
            + ws[WS_LSM + ((size_t)b * 4 + 2) * HH + t] * __expf(l2 - gmax)
            + ws[WS_LSM + ((size_t)b * 4 + 3) * HH + t] * __expf(l3 - gmax);
    float lcx = (cx == 0) ? l0 : (cx == 1) ? l1 : (cx == 2) ? l2 : l3;
    inv_sh[t] = __expf(lcx - gmax) / s;
    w2b_sh[t] = w2b[t];
  }
  __syncthreads();
  for (int i = t; i < HH * HH; i += 256) {
    int g = i >> 5, h = i & 31;
    T2s[i] = (w2W[i] + ((g == h) ? 1.f : 0.f)) * inv_sh[g];
  }
  __syncthreads();

  const int m = cx * 256 + t;
  float* E = ws + WS_E + (size_t)b * (HH * 800);
  float4 av[8];
#pragma unroll
  for (int q = 0; q < 8; ++q) av[q] = make_float4(0.f,0.f,0.f,0.f);
  float rm = 0.f;
  if (m < MM) {
    float rs = ws[WS_RS + (size_t)b * 800 + m];
    rm = ws[WS_RM + (size_t)b * 800 + m];
#pragma unroll 4
    for (int g = 0; g < HH; ++g) {
      float eg = E[(size_t)g * 800 + m];
#pragma unroll
      for (int q = 0; q < 8; ++q) {
        float4 t2 = *(const float4*)&T2s[g * HH + q * 4];
        av[q].x += eg * t2.x; av[q].y += eg * t2.y;
        av[q].z += eg * t2.z; av[q].w += eg * t2.w;
      }
    }
#pragma unroll
    for (int q = 0; q < 8; ++q) {
      av[q].x += w2b_sh[q*4+0]; av[q].y += w2b_sh[q*4+1];
      av[q].z += w2b_sh[q*4+2]; av[q].w += w2b_sh[q*4+3];
      E[(size_t)(q*4+0) * 800 + m] = av[q].x * rs;
      E[(size_t)(q*4+1) * 800 + m] = av[q].y * rs;
      E[(size_t)(q*4+2) * 800 + m] = av[q].z * rs;
      E[(size_t)(q*4+3) * 800 + m] = av[q].w * rs;
    }
  } else if (m < 800) {
#pragma unroll
    for (int h = 0; h < HH; ++h) E[(size_t)h * 800 + m] = 0.f;
  }
  // reduce A2
#pragma unroll
  for (int h = 0; h < HH; ++h) {
    float v = ((const float*)&av[h >> 2])[h & 3];
#pragma unroll
    for (int off = 1; off < 64; off <<= 1) v += __shfl_xor(v, off);
    if (lane == 0) red[wid][h] = v;
  }
  __syncthreads();
  if (t < HH)
    ws[WS_A2P + ((size_t)b * 4 + cx) * HH + t] = red[0][t] + red[1][t] + red[2][t] + red[3][t];
  __syncthreads();
#pragma unroll
  for (int h = 0; h < HH; ++h) {
    float v = ((const float*)&av[h >> 2])[h & 3] * rm;
#pragma unroll
    for (int off = 1; off < 64; off <<= 1) v += __shfl_xor(v, off);
    if (lane == 0) red[wid][h] = v;
  }
  __syncthreads();
  if (t < HH)
    ws[WS_WMP + ((size_t)b * 4 + cx) * HH + t] = red[0][t] + red[1][t] + red[2][t] + red[3][t];
}

// ============================================================
// d6: r[b][h][d] = sum_m w[h][m] * u[m][d]. grid (12 d-tiles of 64, 64).
// u: global->regs (coalesced); w: 4.6KB LDS, f4 reads; msub split + shfl.
// ============================================================
__global__ __launch_bounds__(256) void k_wsum(
    const float* __restrict__ x_cls, const float* __restrict__ x_img,
    float* __restrict__ ws)
{
  const int b = blockIdx.y;
  const int d0 = blockIdx.x * 64;
  const int t = threadIdx.x;
  const int dseg = t & 15;
  const int msub = (t >> 4) & 3;
  const int hb = (t >> 6) * 8;

  __shared__ __align__(16) float w_s[HH][36];
  const float* W = ws + WS_E + (size_t)b * (HH * 800);

  float acc[8][4];
#pragma unroll
  for (int j = 0; j < 8; ++j)
#pragma unroll
    for (int c = 0; c < 4; ++c) acc[j][c] = 0.f;

  float4 pu[8], pun[8];
  float4 pwn;

  auto LOADU = [&](int mc, float4* dst) {
#pragma unroll
    for (int i = 0; i < 8; ++i) {
      int m = mc * 32 + msub * 8 + i;
      if (m < MM) {
        const float* src = (m == 0) ? (x_cls + (size_t)b * DD)
                                    : (x_img + ((size_t)b * NN + (m - 1)) * DD);
        dst[i] = *(const float4*)(src + d0 + dseg * 4);
      } else dst[i] = make_float4(0.f,0.f,0.f,0.f);
    }
  };

  // prologue: chunk 0
  LOADU(0, pu);
  {
    float4 pw = *(const float4*)(W + (size_t)(t >> 3) * 800 + (t & 7) * 4);
    *(float4*)&w_s[t >> 3][(t & 7) * 4] = pw;
  }
  __syncthreads();

  for (int mc = 0; mc < 25; ++mc) {
    if (mc < 24) {
      pwn = *(const float4*)(W + (size_t)(t >> 3) * 800 + (mc + 1) * 32 + (t & 7) * 4);
      LOADU(mc + 1, pun);
    }
#pragma unroll
    for (int j = 0; j < 8; ++j) {
      float4 wA = *(const float4*)&w_s[hb + j][msub * 8];
      float4 wB = *(const float4*)&w_s[hb + j][msub * 8 + 4];
      float wv0 = wA.x, wv1 = wA.y, wv2 = wA.z, wv3 = wA.w;
      float wv4 = wB.x, wv5 = wB.y, wv6 = wB.z, wv7 = wB.w;
      acc[j][0] += wv0*pu[0].x + wv1*pu[1].x + wv2*pu[2].x + wv3*pu[3].x
                 + wv4*pu[4].x + wv5*pu[5].x + wv6*pu[6].x + wv7*pu[7].x;
      acc[j][1] += wv0*pu[0].y + wv1*pu[1].y + wv2*pu[2].y + wv3*pu[3].y
                 + wv4*pu[4].y + wv5*pu[5].y + wv6*pu[6].y + wv7*pu[7].y;
      acc[j][2] += wv0*pu[0].z + wv1*pu[1].z + wv2*pu[2].z + wv3*pu[3].z
                 + wv4*pu[4].z + wv5*pu[5].z + wv6*pu[6].z + wv7*pu[7].z;
      acc[j][3] += wv0*pu[0].w + wv1*pu[1].w + wv2*pu[2].w + wv3*pu[3].w
                 + wv4*pu[4].w + wv5*pu[5].w + wv6*pu[6].w + wv7*pu[7].w;
    }
    __syncthreads();
    if (mc < 24) {
      *(float4*)&w_s[t >> 3][(t & 7) * 4] = pwn;
#pragma unroll
      for (int i = 0; i < 8; ++i) pu[i] = pun[i];
    }
    __syncthreads();
  }

  // reduce over msub (lanes 16, 32 apart)
#pragma unroll
  for (int j = 0; j < 8; ++j)
#pragma unroll
    for (int c = 0; c < 4; ++c) {
      float v = acc[j][c];
      v += __shfl_xor(v, 16);
      v += __shfl_xor(v, 32);
      acc[j][c] = v;
    }
  if (msub == 0) {
    float* R = ws + WS_T + (size_t)b * HH * DD;
#pragma unroll
    for (int j = 0; j < 8; ++j)
      *(float4*)(R + (size_t)(hb + j) * DD + d0 + dseg * 4) =
          make_float4(acc[j][0], acc[j][1], acc[j][2], acc[j][3]);
  }
}

// ============================================================
// d7: o slice per (h,b): agg = g1*(r-WM)+b1*A2;  o = agg@Wv + A2*bv
// ============================================================
__global__ __launch_bounds__(192) void k_att_o(
    const float* __restrict__ g1, const float* __restrict__ b1,
    const float* __restrict__ Wv, const float* __restrict__ bv,
    float* __restrict__ ws)
{
  const int h = blockIdx.x;
  const int b = blockIdx.y;
  const int t = threadIdx.x;

  __shared__ __align__(16) float agg_l[DD];
  __shared__ float red[8][25];
  __shared__ float a2wm[2];

  if (t == 0) {
    float a = 0.f;
#pragma unroll
    for (int c = 0; c < 4; ++c) a += ws[WS_A2P + ((size_t)b * 4 + c) * HH + h];
    a2wm[0] = a;
  }
  if (t == 1) {
    float w = 0.f;
#pragma unroll
    for (int c = 0; c < 4; ++c) w += ws[WS_WMP + ((size_t)b * 4 + c) * HH + h];
    a2wm[1] = w;
  }
  __syncthreads();
  const float A2 = a2wm[0], WM = a2wm[1];
  const float* R = ws + WS_T + ((size_t)b * HH + h) * DD;
  for (int i = t; i < DD; i += 192)
    agg_l[i] = g1[i] * (R[i] - WM) + b1[i] * A2;
  __syncthreads();

  const int oc = t % 24, ks = t / 24;
  const float* wv = Wv + (size_t)(ks * 96) * DD + h * HD24 + oc;
  const float* ag = agg_l + ks * 96;
  float a0 = 0.f, a1 = 0.f, a2 = 0.f, a3 = 0.f;
#pragma unroll 4
  for (int d = 0; d < 96; d += 4) {
    a0 += ag[d + 0] * wv[(size_t)(d + 0) * DD];
    a1 += ag[d + 1] * wv[(size_t)(d + 1) * DD];
    a2 += ag[d + 2] * wv[(size_t)(d + 2) * DD];
    a3 += ag[d + 3] * wv[(size_t)(d + 3) * DD];
  }
  red[ks][oc] = (a0 + a1) + (a2 + a3);
  __syncthreads();
  if (t < 24) {
    float o = A2 * bv[h * HD24 + t];
#pragma unroll
    for (int k = 0; k < 8; ++k) o += red[k][t];
    ws[WS_O + (size_t)b * DD + h * HD24 + t] = o;
  }
}

// ============================================================
// d8: c1 = x_cls + o @ projW + projb  (+ LN2 partial stats). grid (12, 64)
// ============================================================
__global__ __launch_bounds__(256) void k_proj2(
    const float* __restrict__ x_cls,
    const float* __restrict__ projW, const float* __restrict__ projb,
    float* __restrict__ ws)
{
  const int b = blockIdx.y;
  const int oc0 = blockIdx.x * 64;
  const int t = threadIdx.x;

  __shared__ __align__(16) float o_l[DD];
  __shared__ float red4[4][64];

  for (int i = t; i < DD; i += 256) o_l[i] = ws[WS_O + (size_t)b * DD + i];
  __syncthreads();

  const int oc = t & 63, ks = t >> 6;
  const float* wp = projW + (size_t)(ks * 192) * DD + oc0 + oc;
  const float* op = o_l + ks * 192;
  float a0 = 0.f, a1 = 0.f, a2 = 0.f, a3 = 0.f;
#pragma unroll 4
  for (int d = 0; d < 192; d += 4) {
    a0 += op[d + 0] * wp[(size_t)(d + 0) * DD];
    a1 += op[d + 1] * wp[(size_t)(d + 1) * DD];
    a2 += op[d + 2] * wp[(size_t)(d + 2) * DD];
    a3 += op[d + 3] * wp[(size_t)(d + 3) * DD];
  }
  red4[ks][oc] = (a0 + a1) + (a2 + a3);
  __syncthreads();
  if (t < 64) {
    int ocg = oc0 + t;
    float c1 = red4[0][t] + red4[1][t] + red4[2][t] + red4[3][t]
             + projb[ocg] + x_cls[(size_t)b * DD + ocg];
    ws[WS_C1 + (size_t)b * DD + ocg] = c1;
    float cs = c1, cq = c1 * c1;
#pragma unroll
    for (int off = 1; off < 64; off <<= 1) { cs += __shfl_xor(cs, off); cq += __shfl_xor(cq, off); }
    if (t == 0) {
      ws[WS_PS + ((size_t)b * 12 + blockIdx.x) * 2 + 0] = cs;
      ws[WS_PS + ((size_t)b * 12 + blockIdx.x) * 2 + 1] = cq;
    }
  }
}

// ============================================================
// d9: fc1 (grouped, LN2 fused) + exact GELU + channel shuffle. grid 96.
// ============================================================
__global__ __launch_bounds__(256) void k_fc1(
    const float* __restrict__ fc1W, const float* __restrict__ fc1b,
    const float* __restrict__ g2, const float* __restrict__ b2,
    float* __restrict__ ws)
{
  const int g = blockIdx.x / 48;
  const int oc0 = (blockIdx.x % 48) * 32;
  const int t = threadIdx.x;
  const int txo = t & 7, tyb = t >> 3;

  __shared__ float y_s[64][65];
  __shared__ float w_s[32][65];
  __shared__ float mv[64][2];

  if (t < 64) {
    float s = 0.f, q = 0.f;
#pragma unroll
    for (int p = 0; p < 12; ++p) {
      s += ws[WS_PS + ((size_t)t * 12 + p) * 2 + 0];
      q += ws[WS_PS + ((size_t)t * 12 + p) * 2 + 1];
    }
    float mu = s * (1.f / DD);
    mv[t][0] = mu;
    mv[t][1] = rsqrtf(q * (1.f / DD) - mu * mu + LNEPS);
  }
  __syncthreads();

  float acc[2][4];
#pragma unroll
  for (int i = 0; i < 2; ++i)
#pragma unroll
    for (int j = 0; j < 4; ++j) acc[i][j] = 0.f;

#pragma unroll 1
  for (int kc = 0; kc < 6; ++kc) {
    {
      int r = t >> 2;
      float mu = mv[r][0], rs = mv[r][1];
#pragma unroll
      for (int p = 0; p < 4; ++p) {
        int c = (t & 3) * 4 + p * 16;
        int gc = g * 384 + kc * 64 + c;
        float4 v = *(const float4*)(ws + WS_C1 + (size_t)r * DD + gc);
        float4 gg = *(const float4*)(g2 + gc);
        float4 bb = *(const float4*)(b2 + gc);
        y_s[r][c+0] = (v.x - mu) * rs * gg.x + bb.x;
        y_s[r][c+1] = (v.y - mu) * rs * gg.y + bb.y;
        y_s[r][c+2] = (v.z - mu) * rs * gg.z + bb.z;
        y_s[r][c+3] = (v.w - mu) * rs * gg.w + bb.w;
      }
      int rw = t >> 3;
#pragma unroll
      for (int p = 0; p < 2; ++p) {
        int c = (t & 7) * 4 + p * 32;
        float4 w = *(const float4*)(fc1W + ((size_t)(g * 1536 + oc0 + rw)) * 384 + kc * 64 + c);
        w_s[rw][c+0] = w.x; w_s[rw][c+1] = w.y; w_s[rw][c+2] = w.z; w_s[rw][c+3] = w.w;
      }
    }
    __syncthreads();
#pragma unroll 4
    for (int kk = 0; kk < 64; ++kk) {
      float y0 = y_s[2*tyb+0][kk], y1 = y_s[2*tyb+1][kk];
      float w0 = w_s[4*txo+0][kk], w1 = w_s[4*txo+1][kk];
      float w2 = w_s[4*txo+2][kk], w3 = w_s[4*txo+3][kk];
      acc[0][0] += y0*w0; acc[0][1] += y0*w1; acc[0][2] += y0*w2; acc[0][3] += y0*w3;
      acc[1][0] += y1*w0; acc[1][1] += y1*w1; acc[1][2] += y1*w2; acc[1][3] += y1*w3;
    }
    __syncthreads();
  }

  float* H2 = ws + WS_H2;
#pragma unroll
  for (int i = 0; i < 2; ++i) {
    int bb = 2 * tyb + i;
#pragma unroll
    for (int j = 0; j < 4; ++j) {
      int oc = oc0 + 4 * txo + j;
      float v = acc[i][j] + fc1b[g * 1536 + oc];
      v = 0.5f * v * (1.f + erff(v * 0.70710678118654752f));
      H2[(size_t)bb * HIDN + (oc & 1) * 1536 + g * 768 + (oc >> 1)] = v;
    }
  }
}

// ============================================================
// d10: fc2 (grouped, k-split 4). grid (12, 4, 2).
// ============================================================
__global__ __launch_bounds__(256) void k_fc2(
    const float* __restrict__ fc2W, float* __restrict__ ws)
{
  const int oc0 = blockIdx.x * 32;
  const int kq = blockIdx.y;
  const int g = blockIdx.z;
  const int t = threadIdx.x;
  const int txo = t & 7, tyb = t >> 3;

  __shared__ float h_s[64][65];
  __shared__ float w_s[32][65];

  float acc[2][4];
#pragma unroll
  for (int i = 0; i < 2; ++i)
#pragma unroll
    for (int j = 0; j < 4; ++j) acc[i][j] = 0.f;

  const float* H2 = ws + WS_H2;

#pragma unroll 1
  for (int kc = 0; kc < 6; ++kc) {
    {
      int r = t >> 2;
#pragma unroll
      for (int p = 0; p < 4; ++p) {
        int c = (t & 3) * 4 + p * 16;
        float4 v = *(const float4*)(H2 + (size_t)r * HIDN + g * 1536 + kq * 384 + kc * 64 + c);
        h_s[r][c+0] = v.x; h_s[r][c+1] = v.y; h_s[r][c+2] = v.z; h_s[r][c+3] = v.w;
      }
      int rw = t >> 3;
#pragma unroll
      for (int p = 0; p < 2; ++p) {
        int c = (t & 7) * 4 + p * 32;
        float4 w = *(const float4*)(fc2W + ((size_t)(g * 384 + oc0 + rw)) * 1536 + kq * 384 + kc * 64 + c);
        w_s[rw][c+0] = w.x; w_s[rw][c+1] = w.y; w_s[rw][c+2] = w.z; w_s[rw][c+3] = w.w;
      }
    }
    __syncthreads();
#pragma unroll 4
    for (int kk = 0; kk < 64; ++kk) {
      float y0 = h_s[2*tyb+0][kk], y1 = h_s[2*tyb+1][kk];
      float w0 = w_s[4*txo+0][kk], w1 = w_s[4*txo+1][kk];
      float w2 = w_s[4*txo+2][kk], w3 = w_s[4*txo+3][kk];
      acc[0][0] += y0*w0; acc[0][1] += y0*w1; acc[0][2] += y0*w2; acc[0][3] += y0*w3;
      acc[1][0] += y1*w0; acc[1][1] += y1*w1; acc[1][2] += y1*w2; acc[1][3] += y1*w3;
    }
    __syncthreads();
  }

  float* ZP = ws + WS_ZP + (size_t)kq * BB * DD;
#pragma unroll
  for (int i = 0; i < 2; ++i)
#pragma unroll
    for (int j = 0; j < 4; ++j)
      ZP[(size_t)(2 * tyb + i) * DD + g * 384 + oc0 + 4 * txo + j] = acc[i][j];
}

// ============================================================
// d11: out_cls = c1 + fc2_b + sum partials
// ============================================================
__global__ __launch_bounds__(256) void k_final(
    const float* __restrict__ fc2b, float* __restrict__ out, const float* __restrict__ ws)
{
  int idx = blockIdx.x * 256 + threadIdx.x;
  int d = idx % DD;
  float v = ws[WS_C1 + idx] + fc2b[d];
#pragma unroll
  for (int kq = 0; kq < 4; ++kq) v += ws[WS_ZP + (size_t)kq * BB * DD + idx];
  out[idx] = v;
}

extern "C" void kernel_launch(void* const* d_in, const int* in_sizes, int n_in,
                              void* d_out, int out_size, void* d_ws, size_t ws_size,
                              hipStream_t stream)
{
  (void)in_sizes; (void)n_in; (void)out_size; (void)ws_size;
  const float* x_cls = (const float*)d_in[0];
  const float* x_img = (const float*)d_in[1];
  const float* ln1_g = (const float*)d_in[2];
  const float* ln1_b = (const float*)d_in[3];
  const float* Wq    = (const float*)d_in[4];
  const float* bq    = (const float*)d_in[5];
  const float* Wk    = (const float*)d_in[6];
  const float* bk    = (const float*)d_in[7];
  const float* Wv    = (const float*)d_in[8];
  const float* bv    = (const float*)d_in[9];
  const float* w1W   = (const float*)d_in[10];
  const float* w1b   = (const float*)d_in[11];
  const float* w2W   = (const float*)d_in[12];
  const float* w2b   = (const float*)d_in[13];
  const float* projW = (const float*)d_in[14];
  const float* projb = (const float*)d_in[15];
  const float* ln2_g = (const float*)d_in[16];
  const float* ln2_b = (const float*)d_in[17];
  const float* fc1W  = (const float*)d_in[18];
  const float* fc1b  = (const float*)d_in[19];
  const float* fc2W  = (const float*)d_in[20];
  const float* fc2b  = (const float*)d_in[21];
  float* out = (float*)d_out;
  float* ws  = (float*)d_ws;

  k_q    <<<dim3(12, 64), dim3(256), 0, stream>>>(x_cls, ln1_g, ln1_b, Wq, bq, ws);
  k_gqk  <<<dim3(6, 64),  dim3(256), 0, stream>>>(ln1_g, ln1_b, Wk, w1W, ws);
  k_main1<<<dim3(13, 64), dim3(256), 0, stream>>>(x_cls, x_img, out, ws);
  k_sm_a <<<dim3(4, 64),  dim3(256), 0, stream>>>(bk, w1W, w1b, ws);
  k_sm_b <<<dim3(4, 64),  dim3(256), 0, stream>>>(w2W, w2b, ws);
  k_wsum <<<dim3(12, 64), dim3(256), 0, stream>>>(x_cls, x_img, ws);
  k_att_o<<<dim3(32, 64), dim3(192), 0, stream>>>(ln1_g, ln1_b, Wv, bv, ws);
  k_proj2<<<dim3(12, 64), dim3(256), 0, stream>>>(x_cls, projW, projb, ws);
  k_fc1  <<<dim3(96),     dim3(256), 0, stream>>>(fc1W, fc1b, ln2_g, ln2_b, ws);
  k_fc2  <<<dim3(12, 4, 2), dim3(256), 0, stream>>>(fc2W, ws);
  k_final<<<dim3(192),    dim3(256), 0, stream>>>(fc2b, out, ws);
}

// Round 4
// 320.367 us; speedup vs baseline: 4.0654x; 1.0479x over previous
//
#include <hip/hip_runtime.h>
#include <hip/hip_bf16.h>
#include <math.h>

#define BB   64
#define NN   784
#define DD   768
#define HH   32
#define HD24 24
#define MM   785
#define HIDN 3072
#define QSCALE 0.20412414523193154f
#define LNEPS 1e-6f

// ---- workspace layout (float offsets) ----
#define WS_Q     0          // [64][768]   d1..d4 (k_sm_a reads for bqs)
#define WS_RS    49152      // [64][800]   d3..d5
#define WS_RM    100352     // [64][800]
#define WS_S1P   151552     // [64][6][32]
#define WS_BQP   163840     // [64][6][32]
#define WS_LMX   176128     // [64][4][32]
#define WS_LSM   184320
#define WS_A2P   192512
#define WS_WMP   200704
#define WS_PS    208896     // [64][12][2]
#define WS_C1    210432     // [64][768]
#define WS_H2    259584     // [64][3072]
#define WS_O     456192     // [64][768]
#define WS_E     505344     // GQB bf16-frag [64][24][2][64][8] (d2-d3), then E/W [64][32][800] (d4-d6)
#define WS_T     2143744    // t [64][785][32] (d3-d4), then r [64][32][768] (d6-d7)
#define WS_ZP    0          // [4][64][768] overlay (d10-d11)

typedef __attribute__((ext_vector_type(8))) short bf16x8;
typedef __attribute__((ext_vector_type(4))) float f32x4;

__device__ __forceinline__ unsigned packbf(float a, float b) {
  union { __hip_bfloat162 h2; unsigned u; } cv;
  cv.h2 = __float22bfloat162_rn(make_float2(a, b));
  return cv.u;
}
__device__ __forceinline__ float lo16(unsigned w) { return __uint_as_float(w << 16); }
__device__ __forceinline__ float hi16(unsigned w) { return __uint_as_float(w & 0xffff0000u); }

// ============================================================
// d1: q = (LN(x_cls) @ Wq + bq) * QSCALE     grid (12, 64)
// ============================================================
__global__ __launch_bounds__(256) void k_q(
    const float* __restrict__ x_cls,
    const float* __restrict__ g1, const float* __restrict__ b1,
    const float* __restrict__ Wq, const float* __restrict__ bq,
    float* __restrict__ ws)
{
  const int b = blockIdx.y;
  const int oc0 = blockIdx.x * 64;
  const int t = threadIdx.x;
  const int lane = t & 63, wid = t >> 6;

  __shared__ __align__(16) float nc_l[DD];
  __shared__ float red4[4][64];
  __shared__ float rS[4], rQ[4];
  __shared__ float musd[2];

  float xv[3];
  float s = 0.f, q2 = 0.f;
#pragma unroll
  for (int k = 0; k < 3; ++k) {
    float v = x_cls[(size_t)b * DD + t + 256 * k];
    xv[k] = v; s += v; q2 += v * v;
  }
#pragma unroll
  for (int off = 1; off < 64; off <<= 1) { s += __shfl_xor(s, off); q2 += __shfl_xor(q2, off); }
  if (lane == 0) { rS[wid] = s; rQ[wid] = q2; }
  __syncthreads();
  if (t == 0) {
    float ss = rS[0] + rS[1] + rS[2] + rS[3];
    float qq = rQ[0] + rQ[1] + rQ[2] + rQ[3];
    float mu = ss * (1.f / DD);
    musd[0] = mu; musd[1] = rsqrtf(qq * (1.f / DD) - mu * mu + LNEPS);
  }
  __syncthreads();
  {
    float mu = musd[0], rs = musd[1];
#pragma unroll
    for (int k = 0; k < 3; ++k) {
      int d = t + 256 * k;
      nc_l[d] = (xv[k] - mu) * rs * g1[d] + b1[d];
    }
  }
  __syncthreads();

  const int oc = t & 63, ks = t >> 6;
  const float* wp = Wq + (size_t)(ks * 192) * DD + oc0 + oc;
  const float* ncp = nc_l + ks * 192;
  float a0 = 0.f, a1 = 0.f, a2 = 0.f, a3 = 0.f;
#pragma unroll 4
  for (int d = 0; d < 192; d += 4) {
    a0 += ncp[d + 0] * wp[(size_t)(d + 0) * DD];
    a1 += ncp[d + 1] * wp[(size_t)(d + 1) * DD];
    a2 += ncp[d + 2] * wp[(size_t)(d + 2) * DD];
    a3 += ncp[d + 3] * wp[(size_t)(d + 3) * DD];
  }
  red4[ks][oc] = (a0 + a1) + (a2 + a3);
  __syncthreads();
  if (t < 64) {
    int ocg = oc0 + t;
    ws[WS_Q + (size_t)b * DD + ocg] =
        (red4[0][t] + red4[1][t] + red4[2][t] + red4[3][t] + bq[ocg]) * QSCALE;
  }
}

// ============================================================
// d2: gq = fold(T1, qk) ; write bf16 MFMA-B-fragment-swizzled GQB;
// partial s1, bqs.  grid (6 d-tiles of 128, 64)
// B-frag convention (must match k_main1 A-pack): lane = (n&15) + 16*(kk>>3),
// elem j = kk&7, nt = n>>4 — per 32-k step.
// ============================================================
__global__ __launch_bounds__(256) void k_gqk(
    const float* __restrict__ g1, const float* __restrict__ b1,
    const float* __restrict__ Wk, const float* __restrict__ w1W,
    float* __restrict__ ws)
{
  const int b = blockIdx.y;
  const int d0 = blockIdx.x * 128;
  const int t = threadIdx.x;

  __shared__ __align__(16) float q_l[DD];
  __shared__ float T1[HH * HH];
  __shared__ float qk_l[128][33];
  __shared__ float pS[8][HH], pB[8][HH];

  for (int i = t; i < DD; i += 256) q_l[i] = ws[WS_Q + (size_t)b * DD + i];
  for (int i = t; i < HH * HH; i += 256) {
    int g = i >> 5, h = i & 31;
    T1[i] = w1W[i] + ((g == h) ? 1.f : 0.f);
  }
  __syncthreads();

  { // phase 1: qk[d][g] (24-long head dots)
    const int dl = t >> 1, gh = t & 1;
    const float4* wr = (const float4*)(Wk + (size_t)(d0 + dl) * DD + gh * 384);
    const float4* qr = (const float4*)(q_l + gh * 384);
#pragma unroll 4
    for (int gg = 0; gg < 16; ++gg) {
      float a = 0.f;
#pragma unroll
      for (int c = 0; c < 6; ++c) {
        float4 w = wr[gg * 6 + c];
        float4 p = qr[gg * 6 + c];
        a += w.x * p.x + w.y * p.y + w.z * p.z + w.w * p.w;
      }
      qk_l[dl][gh * 16 + gg] = a;
    }
  }
  __syncthreads();
  { // phase 2: mix + write bf16 swizzled GQB + partials
    const int h = t & 31, dg = t >> 5;
    float fb[16];
    float s1a = 0.f, bqa = 0.f;
#pragma unroll 2
    for (int dd = 0; dd < 16; ++dd) {
      int dl = dg * 16 + dd;
      float f = 0.f;
#pragma unroll 8
      for (int g = 0; g < HH; ++g) f += qk_l[dl][g] * T1[g * HH + h];
      float gq = g1[d0 + dl] * f;
      fb[dd] = gq;
      s1a += gq;
      bqa += b1[d0 + dl] * qk_l[dl][h];
    }
    const int kstep = (d0 >> 5) + (dg >> 1);
    const int nt = h >> 4;
    const int lane0 = (h & 15) + 32 * (dg & 1);
    uint4* GQB = (uint4*)(ws + WS_E) + (size_t)b * (24 * 2 * 64);
    GQB[(kstep * 2 + nt) * 64 + lane0] =
        make_uint4(packbf(fb[0], fb[1]), packbf(fb[2], fb[3]),
                   packbf(fb[4], fb[5]), packbf(fb[6], fb[7]));
    GQB[(kstep * 2 + nt) * 64 + lane0 + 16] =
        make_uint4(packbf(fb[8], fb[9]), packbf(fb[10], fb[11]),
                   packbf(fb[12], fb[13]), packbf(fb[14], fb[15]));
    pS[dg][h] = s1a; pB[dg][h] = bqa;
  }
  __syncthreads();
  if (t < HH) {
    float s = 0.f, bq = 0.f;
#pragma unroll
    for (int k = 0; k < 8; ++k) { s += pS[k][t]; bq += pB[k][t]; }
    ws[WS_S1P + ((size_t)b * 6 + blockIdx.x) * HH + t] = s;
    ws[WS_BQP + ((size_t)b * 6 + blockIdx.x) * HH + t] = bq;
  }
}

// ============================================================
// d3: big pass 1 (MFMA). 64 rows/block, grid (13, 64), 4 waves.
// wave w: rows m0+16w..+15, all 32 h via 2 mfma_16x16x32_bf16 per K-step.
// A from global fp32 (cvt bf16), B from GQB (pre-swizzled). Stats ride A-loads.
// Copy x_img->out interleaved per 64-float k-chunk (L1 reuse). No LDS, no barriers.
// ============================================================
__global__ __launch_bounds__(256) void k_main1(
    const float* __restrict__ x_cls, const float* __restrict__ x_img,
    float* __restrict__ out, float* __restrict__ ws)
{
  const int b = blockIdx.y;
  const int m0 = blockIdx.x * 64;
  const int t = threadIdx.x;
  const int w = t >> 6;
  const int l = t & 63;
  const int lg = l >> 4;       // k-subgroup (0..3)
  const int lm = l & 15;       // A-row / B-col within 16-tile

  const uint4* GQ = (const uint4*)(ws + WS_E) + (size_t)b * (24 * 2 * 64);
  float* out_img = out + (size_t)BB * DD;

  const int arow = m0 + w * 16 + lm;
  const bool av = (arow < MM);
  const int arc = av ? arow : 0;
  const float* asrc = (arc == 0) ? (x_cls + (size_t)b * DD)
                                 : (x_img + ((size_t)b * NN + (arc - 1)) * DD);
  const int koff_l = 8 * lg;   // k-offset within each 32-chunk

  f32x4 acc0 = {0.f, 0.f, 0.f, 0.f};
  f32x4 acc1 = {0.f, 0.f, 0.f, 0.f};
  float sl = 0.f, sq = 0.f;

#pragma unroll 1
  for (int kc = 0; kc < 12; ++kc) {
    // ---- copy phase: rows m0..m0+63, cols [kc*64, kc*64+64) ----
#pragma unroll
    for (int p = 0; p < 4; ++p) {
      int i = p * 256 + t;
      int crow = m0 + (i >> 4);
      int cc = i & 15;
      if (crow < MM) {
        const float* src = (crow == 0) ? (x_cls + (size_t)b * DD)
                                       : (x_img + ((size_t)b * NN + (crow - 1)) * DD);
        float4 v = *(const float4*)(src + kc * 64 + cc * 4);
        if (crow >= 1)
          *(float4*)(out_img + ((size_t)b * NN + (crow - 1)) * DD + kc * 64 + cc * 4) = v;
      }
    }
    // ---- mfma phase: 2 K-steps of 32 ----
#pragma unroll
    for (int s = 0; s < 2; ++s) {
      const int kst = kc * 2 + s;
      float4 a0 = make_float4(0.f, 0.f, 0.f, 0.f);
      float4 a1 = make_float4(0.f, 0.f, 0.f, 0.f);
      if (av) {
        a0 = *(const float4*)(asrc + kst * 32 + koff_l);
        a1 = *(const float4*)(asrc + kst * 32 + koff_l + 4);
      }
      sl += (a0.x + a0.y) + (a0.z + a0.w) + (a1.x + a1.y) + (a1.z + a1.w);
      sq += a0.x*a0.x + a0.y*a0.y + a0.z*a0.z + a0.w*a0.w
          + a1.x*a1.x + a1.y*a1.y + a1.z*a1.z + a1.w*a1.w;
      union { uint4 u; bf16x8 h; } ua, ub0, ub1;
      ua.u = make_uint4(packbf(a0.x, a0.y), packbf(a0.z, a0.w),
                        packbf(a1.x, a1.y), packbf(a1.z, a1.w));
      ub0.u = GQ[(kst * 2 + 0) * 64 + l];
      ub1.u = GQ[(kst * 2 + 1) * 64 + l];
      acc0 = __builtin_amdgcn_mfma_f32_16x16x32_bf16(ua.h, ub0.h, acc0, 0, 0, 0);
      acc1 = __builtin_amdgcn_mfma_f32_16x16x32_bf16(ua.h, ub1.h, acc1, 0, 0, 0);
    }
  }

  // ---- stats: lane-groups partition k; combine across lg ----
  sl += __shfl_xor(sl, 16); sl += __shfl_xor(sl, 32);
  sq += __shfl_xor(sq, 16); sq += __shfl_xor(sq, 32);
  if (lg == 0 && av) {
    float mu = sl * (1.f / DD);
    float rs = rsqrtf(sq * (1.f / DD) - mu * mu + LNEPS);
    ws[WS_RS + (size_t)b * 800 + arow] = rs;
    ws[WS_RM + (size_t)b * 800 + arow] = rs * mu;
  }

  // ---- C store: col = lm (+16 for acc1), row = m0+16w+4*lg+r ----
  float* tb = ws + WS_T + (size_t)b * MM * HH;
#pragma unroll
  for (int r = 0; r < 4; ++r) {
    int row = m0 + w * 16 + 4 * lg + r;
    if (row < MM) {
      tb[(size_t)row * HH + lm] = acc0[r];
      tb[(size_t)row * HH + 16 + lm] = acc1[r];
    }
  }
}

// ============================================================
// d4: online softmax pass A. grid (4 m-chunks, 64). attn1 -> e, local max/sum.
// ============================================================
__global__ __launch_bounds__(256) void k_sm_a(
    const float* __restrict__ bk,
    const float* __restrict__ w1W, const float* __restrict__ w1b,
    float* __restrict__ ws)
{
  const int cx = blockIdx.x, b = blockIdx.y;
  const int t = threadIdx.x;
  const int lane = t & 63, wid = t >> 6;

  __shared__ float T1[HH * HH];
  __shared__ float s1_sh[HH], c0_sh[HH], bq_sh[HH];
  __shared__ float red[4][HH];
  __shared__ float lmax_sh[HH];

  for (int i = t; i < HH * HH; i += 256) {
    int g = i >> 5, h = i & 31;
    T1[i] = w1W[i] + ((g == h) ? 1.f : 0.f);
  }
  if (t < HH) {
    float s1v = 0.f, bqv = 0.f;
#pragma unroll
    for (int p = 0; p < 6; ++p) {
      s1v += ws[WS_S1P + ((size_t)b * 6 + p) * HH + t];
      bqv += ws[WS_BQP + ((size_t)b * 6 + p) * HH + t];
    }
    const float* qp = ws + WS_Q + (size_t)b * DD + t * HD24;
#pragma unroll
    for (int j = 0; j < HD24; ++j) bqv += bk[t * HD24 + j] * qp[j];
    s1_sh[t] = s1v; bq_sh[t] = bqv;
  }
  __syncthreads();
  if (t < HH) {
    float c0 = w1b[t];
#pragma unroll
    for (int g = 0; g < HH; ++g) c0 += T1[g * HH + t] * bq_sh[g];
    c0_sh[t] = c0;
  }
  __syncthreads();

  const int m = cx * 256 + t;
  const bool vm = (m < MM);
  float a1[HH];
  if (vm) {
    const float* tb = ws + WS_T + ((size_t)b * MM + m) * HH;
    float rs = ws[WS_RS + (size_t)b * 800 + m];
    float rm = ws[WS_RM + (size_t)b * 800 + m];
#pragma unroll
    for (int q = 0; q < 8; ++q) {
      float4 tv = *(const float4*)(tb + q * 4);
      a1[4*q+0] = rs * tv.x - rm * s1_sh[4*q+0] + c0_sh[4*q+0];
      a1[4*q+1] = rs * tv.y - rm * s1_sh[4*q+1] + c0_sh[4*q+1];
      a1[4*q+2] = rs * tv.z - rm * s1_sh[4*q+2] + c0_sh[4*q+2];
      a1[4*q+3] = rs * tv.w - rm * s1_sh[4*q+3] + c0_sh[4*q+3];
    }
  } else {
#pragma unroll
    for (int h = 0; h < HH; ++h) a1[h] = -3.0e38f;
  }
#pragma unroll
  for (int h = 0; h < HH; ++h) {
    float v = a1[h];
#pragma unroll
    for (int off = 1; off < 64; off <<= 1) v = fmaxf(v, __shfl_xor(v, off));
    if (lane == 0) red[wid][h] = v;
  }
  __syncthreads();
  if (t < HH) {
    float v = fmaxf(fmaxf(red[0][t], red[1][t]), fmaxf(red[2][t], red[3][t]));
    lmax_sh[t] = v;
    ws[WS_LMX + ((size_t)b * 4 + cx) * HH + t] = v;
  }
  __syncthreads();
  float* E = ws + WS_E + (size_t)b * (HH * 800);
  if (vm) {
#pragma unroll
    for (int h = 0; h < HH; ++h) {
      float e = __expf(a1[h] - lmax_sh[h]);
      a1[h] = e;
      E[(size_t)h * 800 + m] = e;
    }
  } else {
#pragma unroll
    for (int h = 0; h < HH; ++h) a1[h] = 0.f;
  }
#pragma unroll
  for (int h = 0; h < HH; ++h) {
    float v = a1[h];
#pragma unroll
    for (int off = 1; off < 64; off <<= 1) v += __shfl_xor(v, off);
    if (lane == 0) red[wid][h] = v;
  }
  __syncthreads();
  if (t < HH)
    ws[WS_LSM + ((size_t)b * 4 + cx) * HH + t] = red[0][t] + red[1][t] + red[2][t] + red[3][t];
}

// ============================================================
// d5: softmax pass B: finalize, post-mix (I+w2)/sum, w = a2*rs into W (=E),
// partial A2/WM. grid (4, 64).
// ============================================================
__global__ __launch_bounds__(256) void k_sm_b(
    const float* __restrict__ w2W, const float* __restrict__ w2b,
    float* __restrict__ ws)
{
  const int cx = blockIdx.x, b = blockIdx.y;
  const int t = threadIdx.x;
  const int lane = t & 63, wid = t >> 6;

  __shared__ __align__(16) float T2s[HH * HH];
  __shared__ float inv_sh[HH], w2b_sh[HH];
  __shared__ float red[4][HH];

  if (t < HH) {
    float l0 = ws[WS_LMX + ((size_t)b * 4 + 0) * HH + t];
    float l1 = ws[WS_LMX + ((size_t)b * 4 + 1) * HH + t];
    float l2 = ws[WS_LMX + ((size_t)b * 4 + 2) * HH + t];
    float l3 = ws[WS_LMX + ((size_t)b * 4 + 3) * HH + t];
    float gmax = fmaxf(fmaxf(l0, l1), fmaxf(l2, l3));
    float s = ws[WS_LSM + ((size_t)b * 4 + 0) * HH + t] * __expf(l0 - gmax)
            + ws[WS_LSM + ((size_t)b * 4 + 1) * HH + t] * __expf(l1 - gmax)
            + ws[WS_LSM + ((size_t)b * 4 + 2) * HH + t] * __expf(l2 - gmax)
            + ws[WS_LSM + ((size_t)b * 4 + 3) * HH + t] * __expf(l3 - gmax);
    float lcx = (cx == 0) ? l0 : (cx == 1) ? l1 : (cx == 2) ? l2 : l3;
    inv_sh[t] = __expf(lcx - gmax) / s;
    w2b_sh[t] = w2b[t];
  }
  __syncthreads();
  for (int i = t; i < HH * HH; i += 256) {
    int g = i >> 5, h = i & 31;
    T2s[i] = (w2W[i] + ((g == h) ? 1.f : 0.f)) * inv_sh[g];
  }
  __syncthreads();

  const int m = cx * 256 + t;
  float* E = ws + WS_E + (size_t)b * (HH * 800);
  float4 av[8];
#pragma unroll
  for (int q = 0; q < 8; ++q) av[q] = make_float4(0.f,0.f,0.f,0.f);
  float rm = 0.f;
  if (m < MM) {
    float rs = ws[WS_RS + (size_t)b * 800 + m];
    rm = ws[WS_RM + (size_t)b * 800 + m];
#pragma unroll 4
    for (int g = 0; g < HH; ++g) {
      float eg = E[(size_t)g * 800 + m];
#pragma unroll
      for (int q = 0; q < 8; ++q) {
        float4 t2 = *(const float4*)&T2s[g * HH + q * 4];
        av[q].x += eg * t2.x; av[q].y += eg * t2.y;
        av[q].z += eg * t2.z; av[q].w += eg * t2.w;
      }
    }
#pragma unroll
    for (int q = 0; q < 8; ++q) {
      av[q].x += w2b_sh[q*4+0]; av[q].y += w2b_sh[q*4+1];
      av[q].z += w2b_sh[q*4+2]; av[q].w += w2b_sh[q*4+3];
      E[(size_t)(q*4+0) * 800 + m] = av[q].x * rs;
      E[(size_t)(q*4+1) * 800 + m] = av[q].y * rs;
      E[(size_t)(q*4+2) * 800 + m] = av[q].z * rs;
      E[(size_t)(q*4+3) * 800 + m] = av[q].w * rs;
    }
  } else if (m < 800) {
#pragma unroll
    for (int h = 0; h < HH; ++h) E[(size_t)h * 800 + m] = 0.f;
  }
#pragma unroll
  for (int h = 0; h < HH; ++h) {
    float v = ((const float*)&av[h >> 2])[h & 3];
#pragma unroll
    for (int off = 1; off < 64; off <<= 1) v += __shfl_xor(v, off);
    if (lane == 0) red[wid][h] = v;
  }
  __syncthreads();
  if (t < HH)
    ws[WS_A2P + ((size_t)b * 4 + cx) * HH + t] = red[0][t] + red[1][t] + red[2][t] + red[3][t];
  __syncthreads();
#pragma unroll
  for (int h = 0; h < HH; ++h) {
    float v = ((const float*)&av[h >> 2])[h & 3] * rm;
#pragma unroll
    for (int off = 1; off < 64; off <<= 1) v += __shfl_xor(v, off);
    if (lane == 0) red[wid][h] = v;
  }
  __syncthreads();
  if (t < HH)
    ws[WS_WMP + ((size_t)b * 4 + cx) * HH + t] = red[0][t] + red[1][t] + red[2][t] + red[3][t];
}

// ============================================================
// d6: r[b][h][d] = sum_m w[h][m] * u[m][d]. grid (12 d-tiles of 64, 64).
// ============================================================
__global__ __launch_bounds__(256) void k_wsum(
    const float* __restrict__ x_cls, const float* __restrict__ x_img,
    float* __restrict__ ws)
{
  const int b = blockIdx.y;
  const int d0 = blockIdx.x * 64;
  const int t = threadIdx.x;
  const int dseg = t & 15;
  const int msub = (t >> 4) & 3;
  const int hb = (t >> 6) * 8;

  __shared__ __align__(16) float w_s[HH][36];
  const float* W = ws + WS_E + (size_t)b * (HH * 800);

  float acc[8][4];
#pragma unroll
  for (int j = 0; j < 8; ++j)
#pragma unroll
    for (int c = 0; c < 4; ++c) acc[j][c] = 0.f;

  float4 pu[8], pun[8];
  float4 pwn;

  auto LOADU = [&](int mc, float4* dst) {
#pragma unroll
    for (int i = 0; i < 8; ++i) {
      int m = mc * 32 + msub * 8 + i;
      if (m < MM) {
        const float* src = (m == 0) ? (x_cls + (size_t)b * DD)
                                    : (x_img + ((size_t)b * NN + (m - 1)) * DD);
        dst[i] = *(const float4*)(src + d0 + dseg * 4);
      } else dst[i] = make_float4(0.f,0.f,0.f,0.f);
    }
  };

  LOADU(0, pu);
  {
    float4 pw = *(const float4*)(W + (size_t)(t >> 3) * 800 + (t & 7) * 4);
    *(float4*)&w_s[t >> 3][(t & 7) * 4] = pw;
  }
  __syncthreads();

  for (int mc = 0; mc < 25; ++mc) {
    if (mc < 24) {
      pwn = *(const float4*)(W + (size_t)(t >> 3) * 800 + (mc + 1) * 32 + (t & 7) * 4);
      LOADU(mc + 1, pun);
    }
#pragma unroll
    for (int j = 0; j < 8; ++j) {
      float4 wA = *(const float4*)&w_s[hb + j][msub * 8];
      float4 wB = *(const float4*)&w_s[hb + j][msub * 8 + 4];
      float wv0 = wA.x, wv1 = wA.y, wv2 = wA.z, wv3 = wA.w;
      float wv4 = wB.x, wv5 = wB.y, wv6 = wB.z, wv7 = wB.w;
      acc[j][0] += wv0*pu[0].x + wv1*pu[1].x + wv2*pu[2].x + wv3*pu[3].x
                 + wv4*pu[4].x + wv5*pu[5].x + wv6*pu[6].x + wv7*pu[7].x;
      acc[j][1] += wv0*pu[0].y + wv1*pu[1].y + wv2*pu[2].y + wv3*pu[3].y
                 + wv4*pu[4].y + wv5*pu[5].y + wv6*pu[6].y + wv7*pu[7].y;
      acc[j][2] += wv0*pu[0].z + wv1*pu[1].z + wv2*pu[2].z + wv3*pu[3].z
                 + wv4*pu[4].z + wv5*pu[5].z + wv6*pu[6].z + wv7*pu[7].z;
      acc[j][3] += wv0*pu[0].w + wv1*pu[1].w + wv2*pu[2].w + wv3*pu[3].w
                 + wv4*pu[4].w + wv5*pu[5].w + wv6*pu[6].w + wv7*pu[7].w;
    }
    __syncthreads();
    if (mc < 24) {
      *(float4*)&w_s[t >> 3][(t & 7) * 4] = pwn;
#pragma unroll
      for (int i = 0; i < 8; ++i) pu[i] = pun[i];
    }
    __syncthreads();
  }

#pragma unroll
  for (int j = 0; j < 8; ++j)
#pragma unroll
    for (int c = 0; c < 4; ++c) {
      float v = acc[j][c];
      v += __shfl_xor(v, 16);
      v += __shfl_xor(v, 32);
      acc[j][c] = v;
    }
  if (msub == 0) {
    float* R = ws + WS_T + (size_t)b * HH * DD;
#pragma unroll
    for (int j = 0; j < 8; ++j)
      *(float4*)(R + (size_t)(hb + j) * DD + d0 + dseg * 4) =
          make_float4(acc[j][0], acc[j][1], acc[j][2], acc[j][3]);
  }
}

// ============================================================
// d7: o slice per (h,b): agg = g1*(r-WM)+b1*A2;  o = agg@Wv + A2*bv
// ============================================================
__global__ __launch_bounds__(192) void k_att_o(
    const float* __restrict__ g1, const float* __restrict__ b1,
    const float* __restrict__ Wv, const float* __restrict__ bv,
    float* __restrict__ ws)
{
  const int h = blockIdx.x;
  const int b = blockIdx.y;
  const int t = threadIdx.x;

  __shared__ __align__(16) float agg_l[DD];
  __shared__ float red[8][25];
  __shared__ float a2wm[2];

  if (t == 0) {
    float a = 0.f;
#pragma unroll
    for (int c = 0; c < 4; ++c) a += ws[WS_A2P + ((size_t)b * 4 + c) * HH + h];
    a2wm[0] = a;
  }
  if (t == 1) {
    float w = 0.f;
#pragma unroll
    for (int c = 0; c < 4; ++c) w += ws[WS_WMP + ((size_t)b * 4 + c) * HH + h];
    a2wm[1] = w;
  }
  __syncthreads();
  const float A2 = a2wm[0], WM = a2wm[1];
  const float* R = ws + WS_T + ((size_t)b * HH + h) * DD;
  for (int i = t; i < DD; i += 192)
    agg_l[i] = g1[i] * (R[i] - WM) + b1[i] * A2;
  __syncthreads();

  const int oc = t % 24, ks = t / 24;
  const float* wv = Wv + (size_t)(ks * 96) * DD + h * HD24 + oc;
  const float* ag = agg_l + ks * 96;
  float a0 = 0.f, a1 = 0.f, a2 = 0.f, a3 = 0.f;
#pragma unroll 4
  for (int d = 0; d < 96; d += 4) {
    a0 += ag[d + 0] * wv[(size_t)(d + 0) * DD];
    a1 += ag[d + 1] * wv[(size_t)(d + 1) * DD];
    a2 += ag[d + 2] * wv[(size_t)(d + 2) * DD];
    a3 += ag[d + 3] * wv[(size_t)(d + 3) * DD];
  }
  red[ks][oc] = (a0 + a1) + (a2 + a3);
  __syncthreads();
  if (t < 24) {
    float o = A2 * bv[h * HD24 + t];
#pragma unroll
    for (int k = 0; k < 8; ++k) o += red[k][t];
    ws[WS_O + (size_t)b * DD + h * HD24 + t] = o;
  }
}

// ============================================================
// d8: c1 = x_cls + o @ projW + projb  (+ LN2 partial stats). grid (12, 64)
// ============================================================
__global__ __launch_bounds__(256) void k_proj2(
    const float* __restrict__ x_cls,
    const float* __restrict__ projW, const float* __restrict__ projb,
    float* __restrict__ ws)
{
  const int b = blockIdx.y;
  const int oc0 = blockIdx.x * 64;
  const int t = threadIdx.x;

  __shared__ __align__(16) float o_l[DD];
  __shared__ float red4[4][64];

  for (int i = t; i < DD; i += 256) o_l[i] = ws[WS_O + (size_t)b * DD + i];
  __syncthreads();

  const int oc = t & 63, ks = t >> 6;
  const float* wp = projW + (size_t)(ks * 192) * DD + oc0 + oc;
  const float* op = o_l + ks * 192;
  float a0 = 0.f, a1 = 0.f, a2 = 0.f, a3 = 0.f;
#pragma unroll 4
  for (int d = 0; d < 192; d += 4) {
    a0 += op[d + 0] * wp[(size_t)(d + 0) * DD];
    a1 += op[d + 1] * wp[(size_t)(d + 1) * DD];
    a2 += op[d + 2] * wp[(size_t)(d + 2) * DD];
    a3 += op[d + 3] * wp[(size_t)(d + 3) * DD];
  }
  red4[ks][oc] = (a0 + a1) + (a2 + a3);
  __syncthreads();
  if (t < 64) {
    int ocg = oc0 + t;
    float c1 = red4[0][t] + red4[1][t] + red4[2][t] + red4[3][t]
             + projb[ocg] + x_cls[(size_t)b * DD + ocg];
    ws[WS_C1 + (size_t)b * DD + ocg] = c1;
    float cs = c1, cq = c1 * c1;
#pragma unroll
    for (int off = 1; off < 64; off <<= 1) { cs += __shfl_xor(cs, off); cq += __shfl_xor(cq, off); }
    if (t == 0) {
      ws[WS_PS + ((size_t)b * 12 + blockIdx.x) * 2 + 0] = cs;
      ws[WS_PS + ((size_t)b * 12 + blockIdx.x) * 2 + 1] = cq;
    }
  }
}

// ============================================================
// d9: fc1 (grouped, LN2 fused) + exact GELU + channel shuffle. grid 96.
// ============================================================
__global__ __launch_bounds__(256) void k_fc1(
    const float* __restrict__ fc1W, const float* __restrict__ fc1b,
    const float* __restrict__ g2, const float* __restrict__ b2,
    float* __restrict__ ws)
{
  const int g = blockIdx.x / 48;
  const int oc0 = (blockIdx.x % 48) * 32;
  const int t = threadIdx.x;
  const int txo = t & 7, tyb = t >> 3;

  __shared__ float y_s[64][65];
  __shared__ float w_s[32][65];
  __shared__ float mv[64][2];

  if (t < 64) {
    float s = 0.f, q = 0.f;
#pragma unroll
    for (int p = 0; p < 12; ++p) {
      s += ws[WS_PS + ((size_t)t * 12 + p) * 2 + 0];
      q += ws[WS_PS + ((size_t)t * 12 + p) * 2 + 1];
    }
    float mu = s * (1.f / DD);
    mv[t][0] = mu;
    mv[t][1] = rsqrtf(q * (1.f / DD) - mu * mu + LNEPS);
  }
  __syncthreads();

  float acc[2][4];
#pragma unroll
  for (int i = 0; i < 2; ++i)
#pragma unroll
    for (int j = 0; j < 4; ++j) acc[i][j] = 0.f;

#pragma unroll 1
  for (int kc = 0; kc < 6; ++kc) {
    {
      int r = t >> 2;
      float mu = mv[r][0], rs = mv[r][1];
#pragma unroll
      for (int p = 0; p < 4; ++p) {
        int c = (t & 3) * 4 + p * 16;
        int gc = g * 384 + kc * 64 + c;
        float4 v = *(const float4*)(ws + WS_C1 + (size_t)r * DD + gc);
        float4 gg = *(const float4*)(g2 + gc);
        float4 bb = *(const float4*)(b2 + gc);
        y_s[r][c+0] = (v.x - mu) * rs * gg.x + bb.x;
        y_s[r][c+1] = (v.y - mu) * rs * gg.y + bb.y;
        y_s[r][c+2] = (v.z - mu) * rs * gg.z + bb.z;
        y_s[r][c+3] = (v.w - mu) * rs * gg.w + bb.w;
      }
      int rw = t >> 3;
#pragma unroll
      for (int p = 0; p < 2; ++p) {
        int c = (t & 7) * 4 + p * 32;
        float4 w = *(const float4*)(fc1W + ((size_t)(g * 1536 + oc0 + rw)) * 384 + kc * 64 + c);
        w_s[rw][c+0] = w.x; w_s[rw][c+1] = w.y; w_s[rw][c+2] = w.z; w_s[rw][c+3] = w.w;
      }
    }
    __syncthreads();
#pragma unroll 4
    for (int kk = 0; kk < 64; ++kk) {
      float y0 = y_s[2*tyb+0][kk], y1 = y_s[2*tyb+1][kk];
      float w0 = w_s[4*txo+0][kk], w1 = w_s[4*txo+1][kk];
      float w2 = w_s[4*txo+2][kk], w3 = w_s[4*txo+3][kk];
      acc[0][0] += y0*w0; acc[0][1] += y0*w1; acc[0][2] += y0*w2; acc[0][3] += y0*w3;
      acc[1][0] += y1*w0; acc[1][1] += y1*w1; acc[1][2] += y1*w2; acc[1][3] += y1*w3;
    }
    __syncthreads();
  }

  float* H2 = ws + WS_H2;
#pragma unroll
  for (int i = 0; i < 2; ++i) {
    int bb = 2 * tyb + i;
#pragma unroll
    for (int j = 0; j < 4; ++j) {
      int oc = oc0 + 4 * txo + j;
      float v = acc[i][j] + fc1b[g * 1536 + oc];
      v = 0.5f * v * (1.f + erff(v * 0.70710678118654752f));
      H2[(size_t)bb * HIDN + (oc & 1) * 1536 + g * 768 + (oc >> 1)] = v;
    }
  }
}

// ============================================================
// d10: fc2 (grouped, k-split 4). grid (12, 4, 2).
// ============================================================
__global__ __launch_bounds__(256) void k_fc2(
    const float* __restrict__ fc2W, float* __restrict__ ws)
{
  const int oc0 = blockIdx.x * 32;
  const int kq = blockIdx.y;
  const int g = blockIdx.z;
  const int t = threadIdx.x;
  const int txo = t & 7, tyb = t >> 3;

  __shared__ float h_s[64][65];
  __shared__ float w_s[32][65];

  float acc[2][4];
#pragma unroll
  for (int i = 0; i < 2; ++i)
#pragma unroll
    for (int j = 0; j < 4; ++j) acc[i][j] = 0.f;

  const float* H2 = ws + WS_H2;

#pragma unroll 1
  for (int kc = 0; kc < 6; ++kc) {
    {
      int r = t >> 2;
#pragma unroll
      for (int p = 0; p < 4; ++p) {
        int c = (t & 3) * 4 + p * 16;
        float4 v = *(const float4*)(H2 + (size_t)r * HIDN + g * 1536 + kq * 384 + kc * 64 + c);
        h_s[r][c+0] = v.x; h_s[r][c+1] = v.y; h_s[r][c+2] = v.z; h_s[r][c+3] = v.w;
      }
      int rw = t >> 3;
#pragma unroll
      for (int p = 0; p < 2; ++p) {
        int c = (t & 7) * 4 + p * 32;
        float4 w = *(const float4*)(fc2W + ((size_t)(g * 384 + oc0 + rw)) * 1536 + kq * 384 + kc * 64 + c);
        w_s[rw][c+0] = w.x; w_s[rw][c+1] = w.y; w_s[rw][c+2] = w.z; w_s[rw][c+3] = w.w;
      }
    }
    __syncthreads();
#pragma unroll 4
    for (int kk = 0; kk < 64; ++kk) {
      float y0 = h_s[2*tyb+0][kk], y1 = h_s[2*tyb+1][kk];
      float w0 = w_s[4*txo+0][kk], w1 = w_s[4*txo+1][kk];
      float w2 = w_s[4*txo+2][kk], w3 = w_s[4*txo+3][kk];
      acc[0][0] += y0*w0; acc[0][1] += y0*w1; acc[0][2] += y0*w2; acc[0][3] += y0*w3;
      acc[1][0] += y1*w0; acc[1][1] += y1*w1; acc[1][2] += y1*w2; acc[1][3] += y1*w3;
    }
    __syncthreads();
  }

  float* ZP = ws + WS_ZP + (size_t)kq * BB * DD;
#pragma unroll
  for (int i = 0; i < 2; ++i)
#pragma unroll
    for (int j = 0; j < 4; ++j)
      ZP[(size_t)(2 * tyb + i) * DD + g * 384 + oc0 + 4 * txo + j] = acc[i][j];
}

// ============================================================
// d11: out_cls = c1 + fc2_b + sum partials
// ============================================================
__global__ __launch_bounds__(256) void k_final(
    const float* __restrict__ fc2b, float* __restrict__ out, const float* __restrict__ ws)
{
  int idx = blockIdx.x * 256 + threadIdx.x;
  int d = idx % DD;
  float v = ws[WS_C1 + idx] + fc2b[d];
#pragma unroll
  for (int kq = 0; kq < 4; ++kq) v += ws[WS_ZP + (size_t)kq * BB * DD + idx];
  out[idx] = v;
}

extern "C" void kernel_launch(void* const* d_in, const int* in_sizes, int n_in,
                              void* d_out, int out_size, void* d_ws, size_t ws_size,
                              hipStream_t stream)
{
  (void)in_sizes; (void)n_in; (void)out_size; (void)ws_size;
  const float* x_cls = (const float*)d_in[0];
  const float* x_img = (const float*)d_in[1];
  const float* ln1_g = (const float*)d_in[2];
  const float* ln1_b = (const float*)d_in[3];
  const float* Wq    = (const float*)d_in[4];
  const float* bq    = (const float*)d_in[5];
  const float* Wk    = (const float*)d_in[6];
  const float* bk    = (const float*)d_in[7];
  const float* Wv    = (const float*)d_in[8];
  const float* bv    = (const float*)d_in[9];
  const float* w1W   = (const float*)d_in[10];
  const float* w1b   = (const float*)d_in[11];
  const float* w2W   = (const float*)d_in[12];
  const float* w2b   = (const float*)d_in[13];
  const float* projW = (const float*)d_in[14];
  const float* projb = (const float*)d_in[15];
  const float* ln2_g = (const float*)d_in[16];
  const float* ln2_b = (const float*)d_in[17];
  const float* fc1W  = (const float*)d_in[18];
  const float* fc1b  = (const float*)d_in[19];
  const float* fc2W  = (const float*)d_in[20];
  const float* fc2b  = (const float*)d_in[21];
  float* out = (float*)d_out;
  float* ws  = (float*)d_ws;

  k_q    <<<dim3(12, 64), dim3(256), 0, stream>>>(x_cls, ln1_g, ln1_b, Wq, bq, ws);
  k_gqk  <<<dim3(6, 64),  dim3(256), 0, stream>>>(ln1_g, ln1_b, Wk, w1W, ws);
  k_main1<<<dim3(13, 64), dim3(256), 0, stream>>>(x_cls, x_img, out, ws);
  k_sm_a <<<dim3(4, 64),  dim3(256), 0, stream>>>(bk, w1W, w1b, ws);
  k_sm_b <<<dim3(4, 64),  dim3(256), 0, stream>>>(w2W, w2b, ws);
  k_wsum <<<dim3(12, 64), dim3(256), 0, stream>>>(x_cls, x_img, ws);
  k_att_o<<<dim3(32, 64), dim3(192), 0, stream>>>(ln1_g, ln1_b, Wv, bv, ws);
  k_proj2<<<dim3(12, 64), dim3(256), 0, stream>>>(x_cls, projW, projb, ws);
  k_fc1  <<<dim3(96),     dim3(256), 0, stream>>>(fc1W, fc1b, ln2_g, ln2_b, ws);
  k_fc2  <<<dim3(12, 4, 2), dim3(256), 0, stream>>>(fc2W, ws);
  k_final<<<dim3(192),    dim3(256), 0, stream>>>(fc2b, out, ws);
}